// Round 1
// baseline (4880.687 us; speedup 1.0000x reference)
//
#include <hip/hip_runtime.h>
#include <hip/hip_bf16.h>
#include <math.h>

// Problem constants (from reference): B=2, S=2048, D=1024, H=16, HD=64, L=4
#define BB 2
#define SS 2048
#define DD 1024
#define HH 16
#define HD 64
#define LL 4
#define BS (BB * SS)          // 4096 tokens
#define FOURD (4 * DD)        // 4096

__device__ __forceinline__ float silu_f(float x) {
    return x / (1.0f + expf(-x));
}

// ---------------------------------------------------------------------------
// RoPE tables: cos/sin [BS][HD]; pos = position_id + 0.1*log(dt+1)
// ---------------------------------------------------------------------------
__global__ __launch_bounds__(256) void rope_table_kernel(
    const float* __restrict__ td, const int* __restrict__ pid,
    float* __restrict__ cosT, float* __restrict__ sinT)
{
    int idx = blockIdx.x * blockDim.x + threadIdx.x;   // over BS*32
    if (idx >= BS * 32) return;
    int i = idx & 31, bs = idx >> 5;
    float pos = (float)pid[bs] + 0.1f * logf(td[bs] + 1.0f);
    float inv = powf(10000.0f, -(float)(2 * i) / 64.0f);
    float f = pos * inv;
    float c = cosf(f), s = sinf(f);
    cosT[bs * HD + i] = c;  cosT[bs * HD + i + 32] = c;
    sinT[bs * HD + i] = s;  sinT[bs * HD + i + 32] = s;
}

// ---------------------------------------------------------------------------
// RMSNorm over D=1024; optional elementwise multiplier (for gate: * silu(u))
// out = w * in * rsqrt(mean(in^2) + eps) [* mul]
// block = 256 threads, one row per block, float4 per thread
// ---------------------------------------------------------------------------
__global__ __launch_bounds__(256) void rmsnorm_kernel(
    const float* __restrict__ in, const float* __restrict__ w,
    const float* __restrict__ mul, int mulStride,
    float* __restrict__ out)
{
    __shared__ float red[4];
    int row = blockIdx.x, t = threadIdx.x;
    const float4 v = *(const float4*)&in[(size_t)row * DD + t * 4];
    float ss = v.x * v.x + v.y * v.y + v.z * v.z + v.w * v.w;
    #pragma unroll
    for (int o = 32; o > 0; o >>= 1) ss += __shfl_down(ss, o);
    if ((t & 63) == 0) red[t >> 6] = ss;
    __syncthreads();
    float tot = red[0] + red[1] + red[2] + red[3];
    float r = rsqrtf(tot * (1.0f / (float)DD) + 1e-6f);
    const float4 wv = *(const float4*)&w[t * 4];
    float4 o4;
    o4.x = v.x * r * wv.x;  o4.y = v.y * r * wv.y;
    o4.z = v.z * r * wv.z;  o4.w = v.w * r * wv.w;
    if (mul) {
        const float4 m = *(const float4*)&mul[(size_t)row * mulStride + t * 4];
        o4.x *= m.x; o4.y *= m.y; o4.z *= m.z; o4.w *= m.w;
    }
    *(float4*)&out[(size_t)row * DD + t * 4] = o4;
}

// ---------------------------------------------------------------------------
// fp32 GEMM: C[M,N] = A[M,K] @ W[K,N] + bias[N] (+ residual[M,N])
// 128x128 tile, 256 threads, 8x8 per thread, BK=8
// ---------------------------------------------------------------------------
#define GBM 128
#define GBN 128
#define GBK 8
__global__ __launch_bounds__(256) void gemm_kernel(
    const float* __restrict__ A, const float* __restrict__ W,
    const float* __restrict__ bias, const float* __restrict__ res,
    float* __restrict__ C, int M, int N, int K)
{
    __shared__ float As[GBK][GBM];
    __shared__ float Bs[GBK][GBN];
    const int tid = threadIdx.x;
    const int tx = tid & 15, ty = tid >> 4;
    const int m0 = blockIdx.y * GBM, n0 = blockIdx.x * GBN;

    float acc[8][8] = {};

    const int arow = tid >> 1, ac0 = (tid & 1) * 4;   // A tile: 128 rows x 8 k
    const int brow = tid >> 5, bc0 = (tid & 31) * 4;  // B tile: 8 k x 128 cols

    for (int k0 = 0; k0 < K; k0 += GBK) {
        const float4 av = *(const float4*)&A[(size_t)(m0 + arow) * K + k0 + ac0];
        As[ac0 + 0][arow] = av.x;
        As[ac0 + 1][arow] = av.y;
        As[ac0 + 2][arow] = av.z;
        As[ac0 + 3][arow] = av.w;
        const float4 bv = *(const float4*)&W[(size_t)(k0 + brow) * N + n0 + bc0];
        *(float4*)&Bs[brow][bc0] = bv;
        __syncthreads();
        #pragma unroll
        for (int kk = 0; kk < GBK; ++kk) {
            float a[8], b[8];
            #pragma unroll
            for (int i = 0; i < 8; ++i) a[i] = As[kk][ty * 8 + i];
            #pragma unroll
            for (int j = 0; j < 8; ++j) b[j] = Bs[kk][tx + 16 * j];
            #pragma unroll
            for (int i = 0; i < 8; ++i)
                #pragma unroll
                for (int j = 0; j < 8; ++j)
                    acc[i][j] += a[i] * b[j];
        }
        __syncthreads();
    }

    #pragma unroll
    for (int i = 0; i < 8; ++i) {
        const int row = m0 + ty * 8 + i;
        #pragma unroll
        for (int j = 0; j < 8; ++j) {
            const int col = n0 + tx + 16 * j;
            float v = acc[i][j] + bias[col];
            if (res) v += res[(size_t)row * N + col];
            C[(size_t)row * N + col] = v;
        }
    }
}

// ---------------------------------------------------------------------------
// Post-process uvqk in place: u <- silu(u); q,k <- RoPE(q,k)
// one block per token, 256 threads
// ---------------------------------------------------------------------------
__global__ __launch_bounds__(256) void postproc_kernel(
    float* __restrict__ uvqk,
    const float* __restrict__ cosT, const float* __restrict__ sinT)
{
    const int bs = blockIdx.x, t = threadIdx.x;
    float* base = uvqk + (size_t)bs * FOURD;

    // silu on u (section 0): 4 elems/thread
    float4 u = *(float4*)&base[t * 4];
    u.x = silu_f(u.x); u.y = silu_f(u.y); u.z = silu_f(u.z); u.w = silu_f(u.w);
    *(float4*)&base[t * 4] = u;

    // RoPE on q (section 2) and k (section 3).
    // thread handles head hh = t/16, pair indices p, p+1 (p = (t%16)*2)
    const int hh = t >> 4, p = (t & 15) * 2;
    const float c0 = cosT[bs * HD + p], c1 = cosT[bs * HD + p + 1];
    const float s0 = sinT[bs * HD + p], s1 = sinT[bs * HD + p + 1];
    #pragma unroll
    for (int sect = 2; sect <= 3; ++sect) {
        float* qp = base + sect * DD + hh * HD;
        const float a0 = qp[p], a1 = qp[p + 1];
        const float b0 = qp[p + 32], b1 = qp[p + 33];
        qp[p]      = a0 * c0 - b0 * s0;
        qp[p + 1]  = a1 * c1 - b1 * s1;
        qp[p + 32] = b0 * c0 + a0 * s0;
        qp[p + 33] = b1 * c1 + a1 * s1;
    }
}

// ---------------------------------------------------------------------------
// Causal SiLU attention: out[b,q,h,:] = sum_{k<=q} silu(q.k * scale) * v[k]
// 64 queries x 64 keys tiles; Q/K/V/S tiles in LDS (padded stride 68)
// grid: (S/64, H, B), 256 threads
// ---------------------------------------------------------------------------
#define APAD 68
__global__ __launch_bounds__(256) void attn_kernel(
    const float* __restrict__ uvqk, float* __restrict__ attnOut)
{
    __shared__ float Qs[64][APAD];
    __shared__ float Ks[64][APAD];
    __shared__ float Vs[64][APAD];
    __shared__ float Sw[64][APAD];

    const int qt = blockIdx.x, h = blockIdx.y, b = blockIdx.z;
    const int tid = threadIdx.x, tx = tid & 15, ty = tid >> 4;

    const size_t rs = FOURD;
    const float* qbase = uvqk + (size_t)b * SS * rs + 2 * DD + h * HD;
    const float* kbase = uvqk + (size_t)b * SS * rs + 3 * DD + h * HD;
    const float* vbase = uvqk + (size_t)b * SS * rs + 1 * DD + h * HD;

    // stage Q tile (once)
    #pragma unroll
    for (int r = 0; r < 4; ++r) {
        const int idx = tid + 256 * r;          // 0..1023
        const int tok = idx >> 4, d4 = (idx & 15) * 4;
        *(float4*)&Qs[tok][d4] =
            *(const float4*)&qbase[(size_t)(qt * 64 + tok) * rs + d4];
    }

    float acc[4][4] = {};

    for (int kt = 0; kt <= qt; ++kt) {
        __syncthreads();   // Qs ready (iter 0) / Ks,Vs,Sw free (iter >0)
        #pragma unroll
        for (int r = 0; r < 4; ++r) {
            const int idx = tid + 256 * r;
            const int tok = idx >> 4, d4 = (idx & 15) * 4;
            *(float4*)&Ks[tok][d4] =
                *(const float4*)&kbase[(size_t)(kt * 64 + tok) * rs + d4];
            *(float4*)&Vs[tok][d4] =
                *(const float4*)&vbase[(size_t)(kt * 64 + tok) * rs + d4];
        }
        __syncthreads();

        // phase A: scores s[i][j] = Q[ty*4+i] . K[tx+16j]
        float s[4][4] = {};
        for (int d = 0; d < 64; ++d) {
            float qv[4], kv[4];
            #pragma unroll
            for (int i = 0; i < 4; ++i) qv[i] = Qs[ty * 4 + i][d];
            #pragma unroll
            for (int j = 0; j < 4; ++j) kv[j] = Ks[tx + 16 * j][d];
            #pragma unroll
            for (int i = 0; i < 4; ++i)
                #pragma unroll
                for (int j = 0; j < 4; ++j)
                    s[i][j] += qv[i] * kv[j];
        }
        #pragma unroll
        for (int i = 0; i < 4; ++i) {
            #pragma unroll
            for (int j = 0; j < 4; ++j) {
                const float sc = s[i][j] * 0.125f;   // 1/sqrt(64)
                float wgt = silu_f(sc);
                const int qrow = qt * 64 + ty * 4 + i;
                const int kcol = kt * 64 + tx + 16 * j;
                if (kcol > qrow) wgt = 0.0f;         // causal
                Sw[ty * 4 + i][tx + 16 * j] = wgt;
            }
        }
        __syncthreads();

        // phase B: acc[i][j] += sum_k Sw[ty*4+i][k] * Vs[k][tx+16j]
        for (int k = 0; k < 64; ++k) {
            float wv[4], vv[4];
            #pragma unroll
            for (int i = 0; i < 4; ++i) wv[i] = Sw[ty * 4 + i][k];
            #pragma unroll
            for (int j = 0; j < 4; ++j) vv[j] = Vs[k][tx + 16 * j];
            #pragma unroll
            for (int i = 0; i < 4; ++i)
                #pragma unroll
                for (int j = 0; j < 4; ++j)
                    acc[i][j] += wv[i] * vv[j];
        }
    }

    // write attention output [BS][D]: row = b*S + qt*64 + ty*4+i, col = h*64 + tx+16j
    #pragma unroll
    for (int i = 0; i < 4; ++i) {
        const int row = b * SS + qt * 64 + ty * 4 + i;
        #pragma unroll
        for (int j = 0; j < 4; ++j) {
            attnOut[(size_t)row * DD + h * HD + tx + 16 * j] = acc[i][j];
        }
    }
}

// ---------------------------------------------------------------------------
// launch
// ---------------------------------------------------------------------------
extern "C" void kernel_launch(void* const* d_in, const int* in_sizes, int n_in,
                              void* d_out, int out_size, void* d_ws, size_t ws_size,
                              hipStream_t stream) {
    const float* x         = (const float*)d_in[0];
    const float* td        = (const float*)d_in[1];
    // d_in[2] = attn_mask (causal tril) — implemented via predicate
    const float* uvqk_w    = (const float*)d_in[3];
    const float* uvqk_b    = (const float*)d_in[4];
    const float* gate_w    = (const float*)d_in[5];
    const float* out_w     = (const float*)d_in[6];
    const float* out_b     = (const float*)d_in[7];
    const float* in_norm_w = (const float*)d_in[8];
    const float* last_norm_w = (const float*)d_in[9];
    const int*   pid       = (const int*)d_in[10];
    float* out = (float*)d_out;
    float* ws  = (float*)d_ws;

    // workspace layout (floats)
    float* cosT = ws;                              // BS*HD   = 262144
    float* sinT = cosT + (size_t)BS * HD;          // 262144
    float* h    = sinT + (size_t)BS * HD;          // BS*D    = 4194304
    float* uvqk = h    + (size_t)BS * DD;          // BS*4D   = 16777216
    float* attn = uvqk + (size_t)BS * FOURD;       // BS*D    = 4194304
    // total ~102.8 MB

    rope_table_kernel<<<(BS * 32 + 255) / 256, 256, 0, stream>>>(td, pid, cosT, sinT);
    rmsnorm_kernel<<<BS, 256, 0, stream>>>(x, in_norm_w, nullptr, 0, h);

    for (int l = 0; l < LL; ++l) {
        // uvqk = h @ uvqk_w[l] + uvqk_b[l]
        gemm_kernel<<<dim3(FOURD / GBN, BS / GBM), 256, 0, stream>>>(
            h, uvqk_w + (size_t)l * DD * FOURD, uvqk_b + (size_t)l * FOURD,
            nullptr, uvqk, BS, FOURD, DD);
        // u <- silu(u); q,k <- rope(q,k)
        postproc_kernel<<<BS, 256, 0, stream>>>(uvqk, cosT, sinT);
        // attn = causal silu-attention(q, k, v)
        attn_kernel<<<dim3(SS / 64, HH, BB), 256, 0, stream>>>(uvqk, attn);
        // gated = rmsnorm(attn, gate_w[l]) * u   (in place over attn)
        rmsnorm_kernel<<<BS, 256, 0, stream>>>(
            attn, gate_w + (size_t)l * DD, uvqk /*u section*/, FOURD, attn);
        // h = h + gated @ out_w[l] + out_b[l]
        gemm_kernel<<<dim3(DD / GBN, BS / GBM), 256, 0, stream>>>(
            attn, out_w + (size_t)l * DD * DD, out_b + (size_t)l * DD,
            h /*residual*/, h, BS, DD, DD);
    }

    rmsnorm_kernel<<<BS, 256, 0, stream>>>(h, last_norm_w, nullptr, 0, out);
}

// Round 2
// 3169.943 us; speedup vs baseline: 1.5397x; 1.5397x over previous
//
#include <hip/hip_runtime.h>
#include <hip/hip_bf16.h>
#include <math.h>

// Problem constants: B=2, S=2048, D=1024, H=16, HD=64, L=4
#define BB 2
#define SS 2048
#define DD 1024
#define HH 16
#define HD 64
#define LL 4
#define BS (BB * SS)          // 4096 tokens
#define FOURD (4 * DD)        // 4096

typedef unsigned int u32;
typedef unsigned short ushort_t;
typedef __attribute__((ext_vector_type(8))) short bf16x8;
typedef __attribute__((ext_vector_type(4))) float f32x4;

__device__ __forceinline__ float silu_f(float x) {
    return x / (1.0f + expf(-x));
}

// bf16 round-to-nearest-even split helpers
__device__ __forceinline__ ushort_t f2bf(float x) {
    u32 u = __float_as_uint(x);
    u32 r = (u + 0x7fffu + ((u >> 16) & 1u)) >> 16;
    return (ushort_t)r;
}
__device__ __forceinline__ float bf2f(ushort_t h) {
    return __uint_as_float((u32)h << 16);
}

// async global->LDS, 16B per lane; lds dest is wave-uniform base + lane*16
typedef __attribute__((address_space(3))) u32 lds_u32;
typedef const __attribute__((address_space(1))) u32 glb_u32;
__device__ __forceinline__ void gload16(const void* g, const void* lds) {
    __builtin_amdgcn_global_load_lds((glb_u32*)(uintptr_t)g,
                                     (lds_u32*)(uintptr_t)lds, 16, 0, 0);
}

#define MFMA16(a, b, c) __builtin_amdgcn_mfma_f32_16x16x32_bf16((a), (b), (c), 0, 0, 0)

// ---------------------------------------------------------------------------
// RoPE tables: cos/sin [BS][HD]; pos = position_id + 0.1*log(dt+1)
// ---------------------------------------------------------------------------
__global__ __launch_bounds__(256) void rope_table_kernel(
    const float* __restrict__ td, const int* __restrict__ pid,
    float* __restrict__ cosT, float* __restrict__ sinT)
{
    int idx = blockIdx.x * blockDim.x + threadIdx.x;   // over BS*32
    if (idx >= BS * 32) return;
    int i = idx & 31, bs = idx >> 5;
    float pos = (float)pid[bs] + 0.1f * logf(td[bs] + 1.0f);
    float inv = powf(10000.0f, -(float)(2 * i) / 64.0f);
    float f = pos * inv;
    float c = cosf(f), s = sinf(f);
    cosT[bs * HD + i] = c;  cosT[bs * HD + i + 32] = c;
    sinT[bs * HD + i] = s;  sinT[bs * HD + i + 32] = s;
}

// ---------------------------------------------------------------------------
// RMSNorm over D=1024; optional elementwise multiplier; optional bf16 hi/lo
// split outputs (feed the MFMA GEMM without an extra pass)
// ---------------------------------------------------------------------------
__global__ __launch_bounds__(256) void rmsnorm_kernel(
    const float* __restrict__ in, const float* __restrict__ w,
    const float* __restrict__ mul, int mulStride,
    float* __restrict__ out,
    ushort_t* __restrict__ hi, ushort_t* __restrict__ lo)
{
    __shared__ float red[4];
    int row = blockIdx.x, t = threadIdx.x;
    const float4 v = *(const float4*)&in[(size_t)row * DD + t * 4];
    float ss = v.x * v.x + v.y * v.y + v.z * v.z + v.w * v.w;
    #pragma unroll
    for (int o = 32; o > 0; o >>= 1) ss += __shfl_down(ss, o);
    if ((t & 63) == 0) red[t >> 6] = ss;
    __syncthreads();
    float tot = red[0] + red[1] + red[2] + red[3];
    float r = rsqrtf(tot * (1.0f / (float)DD) + 1e-6f);
    const float4 wv = *(const float4*)&w[t * 4];
    float4 o4;
    o4.x = v.x * r * wv.x;  o4.y = v.y * r * wv.y;
    o4.z = v.z * r * wv.z;  o4.w = v.w * r * wv.w;
    if (mul) {
        const float4 m = *(const float4*)&mul[(size_t)row * mulStride + t * 4];
        o4.x *= m.x; o4.y *= m.y; o4.z *= m.z; o4.w *= m.w;
    }
    const size_t o = (size_t)row * DD + t * 4;
    *(float4*)&out[o] = o4;
    if (hi) {
        ushort4 h4, l4;
        float e;
        h4.x = f2bf(o4.x); e = o4.x - bf2f(h4.x); l4.x = f2bf(e);
        h4.y = f2bf(o4.y); e = o4.y - bf2f(h4.y); l4.y = f2bf(e);
        h4.z = f2bf(o4.z); e = o4.z - bf2f(h4.z); l4.z = f2bf(e);
        h4.w = f2bf(o4.w); e = o4.w - bf2f(h4.w); l4.w = f2bf(e);
        *(ushort4*)&hi[o] = h4;
        *(ushort4*)&lo[o] = l4;
    }
}

// ---------------------------------------------------------------------------
// Weight transpose + bf16 split: W [K][N] fp32 -> Wt_hi/Wt_lo [N][K] bf16
// grid (N/32, K/32), 256 threads
// ---------------------------------------------------------------------------
__global__ __launch_bounds__(256) void wsplit_kernel(
    const float* __restrict__ W, ushort_t* __restrict__ hi,
    ushort_t* __restrict__ lo, int K, int N)
{
    __shared__ float T[32][33];
    const int n0 = blockIdx.x * 32, k0 = blockIdx.y * 32;
    const int t = threadIdx.x;
    {
        const int r = t >> 3, cg = (t & 7) * 4;
        const float4 v = *(const float4*)&W[(size_t)(k0 + r) * N + n0 + cg];
        T[r][cg] = v.x; T[r][cg + 1] = v.y; T[r][cg + 2] = v.z; T[r][cg + 3] = v.w;
    }
    __syncthreads();
    {
        const int n = t >> 3, kg = (t & 7) * 4;
        ushort4 h4, l4;
        float x, e;
        x = T[kg + 0][n]; h4.x = f2bf(x); e = x - bf2f(h4.x); l4.x = f2bf(e);
        x = T[kg + 1][n]; h4.y = f2bf(x); e = x - bf2f(h4.y); l4.y = f2bf(e);
        x = T[kg + 2][n]; h4.z = f2bf(x); e = x - bf2f(h4.z); l4.z = f2bf(e);
        x = T[kg + 3][n]; h4.w = f2bf(x); e = x - bf2f(h4.w); l4.w = f2bf(e);
        const size_t o = (size_t)(n0 + n) * K + k0 + kg;
        *(ushort4*)&hi[o] = h4;
        *(ushort4*)&lo[o] = l4;
    }
}

// ---------------------------------------------------------------------------
// bf16x3 MFMA GEMM: C[M,N] = (Ah+Al)[M,K] @ (Bh+Bl)^T[K,N] + bias (+res)
//   A given as hi/lo bf16 [M][K]; B given as W^T hi/lo bf16 [N][K].
//   Products kept: hi*hi + hi*lo + lo*hi (fp32 acc) ~ 1e-5 rel error.
// 128x128 tile, BK=32, 256 threads (4 waves, each 64x64), mfma 16x16x32.
// Optional split epilogue emits C as bf16 hi/lo for the next GEMM.
// ---------------------------------------------------------------------------
#define TBM 128
#define TBN 128
#define TBK 32
__global__ __launch_bounds__(256) void gemm3_kernel(
    const ushort_t* __restrict__ Ah, const ushort_t* __restrict__ Al,
    const ushort_t* __restrict__ Bh, const ushort_t* __restrict__ Bl,
    const float* __restrict__ bias, const float* __restrict__ res,
    float* __restrict__ C, ushort_t* __restrict__ Chi, ushort_t* __restrict__ Clo,
    int M, int N, int K)
{
    __shared__ ushort_t sAh[TBM][TBK];
    __shared__ ushort_t sAl[TBM][TBK];
    __shared__ ushort_t sBh[TBN][TBK];
    __shared__ ushort_t sBl[TBN][TBK];

    const int tid = threadIdx.x;
    const int w = tid >> 6, l = tid & 63;
    const int wr = w >> 1, wc = w & 1;           // wave sub-tile (64x64)
    const int m0 = blockIdx.y * TBM, n0 = blockIdx.x * TBN;
    const int lr = l & 15, lk = (l >> 4) * 8;

    f32x4 acc[4][4];
    #pragma unroll
    for (int m = 0; m < 4; ++m)
        #pragma unroll
        for (int n = 0; n < 4; ++n)
            acc[m][n] = (f32x4){0.f, 0.f, 0.f, 0.f};

    for (int k0 = 0; k0 < K; k0 += TBK) {
        if (k0) __syncthreads();
        // stage 4 tiles of 8KB each; 512 16B-chunks per tile, 2 per thread
        #pragma unroll
        for (int i = 0; i < 2; ++i) {
            const int cb = i * 256 + w * 64;      // wave-uniform chunk base
            const int chunk = cb + l;             // per-lane chunk
            const int row = chunk >> 2;
            const int kc = (chunk & 3) * 8;
            const size_t ga = (size_t)(m0 + row) * K + k0 + kc;
            const size_t gb = (size_t)(n0 + row) * K + k0 + kc;
            gload16(Ah + ga, &sAh[0][0] + (size_t)cb * 8);
            gload16(Al + ga, &sAl[0][0] + (size_t)cb * 8);
            gload16(Bh + gb, &sBh[0][0] + (size_t)cb * 8);
            gload16(Bl + gb, &sBl[0][0] + (size_t)cb * 8);
        }
        __syncthreads();

        bf16x8 ah[4], al[4], bh[4], bl[4];
        #pragma unroll
        for (int m = 0; m < 4; ++m) {
            ah[m] = *(const bf16x8*)&sAh[wr * 64 + m * 16 + lr][lk];
            al[m] = *(const bf16x8*)&sAl[wr * 64 + m * 16 + lr][lk];
        }
        #pragma unroll
        for (int n = 0; n < 4; ++n) {
            bh[n] = *(const bf16x8*)&sBh[wc * 64 + n * 16 + lr][lk];
            bl[n] = *(const bf16x8*)&sBl[wc * 64 + n * 16 + lr][lk];
        }
        #pragma unroll
        for (int m = 0; m < 4; ++m) {
            #pragma unroll
            for (int n = 0; n < 4; ++n) {
                acc[m][n] = MFMA16(ah[m], bh[n], acc[m][n]);
                acc[m][n] = MFMA16(al[m], bh[n], acc[m][n]);
                acc[m][n] = MFMA16(ah[m], bl[n], acc[m][n]);
            }
        }
    }

    // epilogue: C/D layout col=lane&15, row=(lane>>4)*4+r  [m89-verified]
    #pragma unroll
    for (int m = 0; m < 4; ++m) {
        #pragma unroll
        for (int n = 0; n < 4; ++n) {
            const int col = n0 + wc * 64 + n * 16 + lr;
            #pragma unroll
            for (int r = 0; r < 4; ++r) {
                const int row = m0 + wr * 64 + m * 16 + (l >> 4) * 4 + r;
                const size_t o = (size_t)row * N + col;
                float v = acc[m][n][r] + bias[col];
                if (res) v += res[o];
                C[o] = v;
                if (Chi) {
                    ushort_t hv = f2bf(v);
                    Chi[o] = hv;
                    Clo[o] = f2bf(v - bf2f(hv));
                }
            }
        }
    }
}

// ---------------------------------------------------------------------------
// Post-process uvqk in place: u <- silu(u); q,k <- RoPE(q,k)
// ---------------------------------------------------------------------------
__global__ __launch_bounds__(256) void postproc_kernel(
    float* __restrict__ uvqk,
    const float* __restrict__ cosT, const float* __restrict__ sinT)
{
    const int bs = blockIdx.x, t = threadIdx.x;
    float* base = uvqk + (size_t)bs * FOURD;

    float4 u = *(float4*)&base[t * 4];
    u.x = silu_f(u.x); u.y = silu_f(u.y); u.z = silu_f(u.z); u.w = silu_f(u.w);
    *(float4*)&base[t * 4] = u;

    const int hh = t >> 4, p = (t & 15) * 2;
    const float c0 = cosT[bs * HD + p], c1 = cosT[bs * HD + p + 1];
    const float s0 = sinT[bs * HD + p], s1 = sinT[bs * HD + p + 1];
    #pragma unroll
    for (int sect = 2; sect <= 3; ++sect) {
        float* qp = base + sect * DD + hh * HD;
        const float a0 = qp[p], a1 = qp[p + 1];
        const float b0 = qp[p + 32], b1 = qp[p + 33];
        qp[p]      = a0 * c0 - b0 * s0;
        qp[p + 1]  = a1 * c1 - b1 * s1;
        qp[p + 32] = b0 * c0 + a0 * s0;
        qp[p + 33] = b1 * c1 + a1 * s1;
    }
}

// ---------------------------------------------------------------------------
// Causal SiLU attention (fp32, unchanged this round)
// ---------------------------------------------------------------------------
#define APAD 68
__global__ __launch_bounds__(256) void attn_kernel(
    const float* __restrict__ uvqk, float* __restrict__ attnOut)
{
    __shared__ float Qs[64][APAD];
    __shared__ float Ks[64][APAD];
    __shared__ float Vs[64][APAD];
    __shared__ float Sw[64][APAD];

    const int qt = blockIdx.x, h = blockIdx.y, b = blockIdx.z;
    const int tid = threadIdx.x, tx = tid & 15, ty = tid >> 4;

    const size_t rs = FOURD;
    const float* qbase = uvqk + (size_t)b * SS * rs + 2 * DD + h * HD;
    const float* kbase = uvqk + (size_t)b * SS * rs + 3 * DD + h * HD;
    const float* vbase = uvqk + (size_t)b * SS * rs + 1 * DD + h * HD;

    #pragma unroll
    for (int r = 0; r < 4; ++r) {
        const int idx = tid + 256 * r;
        const int tok = idx >> 4, d4 = (idx & 15) * 4;
        *(float4*)&Qs[tok][d4] =
            *(const float4*)&qbase[(size_t)(qt * 64 + tok) * rs + d4];
    }

    float acc[4][4] = {};

    for (int kt = 0; kt <= qt; ++kt) {
        __syncthreads();
        #pragma unroll
        for (int r = 0; r < 4; ++r) {
            const int idx = tid + 256 * r;
            const int tok = idx >> 4, d4 = (idx & 15) * 4;
            *(float4*)&Ks[tok][d4] =
                *(const float4*)&kbase[(size_t)(kt * 64 + tok) * rs + d4];
            *(float4*)&Vs[tok][d4] =
                *(const float4*)&vbase[(size_t)(kt * 64 + tok) * rs + d4];
        }
        __syncthreads();

        float s[4][4] = {};
        for (int d = 0; d < 64; ++d) {
            float qv[4], kv[4];
            #pragma unroll
            for (int i = 0; i < 4; ++i) qv[i] = Qs[ty * 4 + i][d];
            #pragma unroll
            for (int j = 0; j < 4; ++j) kv[j] = Ks[tx + 16 * j][d];
            #pragma unroll
            for (int i = 0; i < 4; ++i)
                #pragma unroll
                for (int j = 0; j < 4; ++j)
                    s[i][j] += qv[i] * kv[j];
        }
        #pragma unroll
        for (int i = 0; i < 4; ++i) {
            #pragma unroll
            for (int j = 0; j < 4; ++j) {
                const float sc = s[i][j] * 0.125f;
                float wgt = silu_f(sc);
                const int qrow = qt * 64 + ty * 4 + i;
                const int kcol = kt * 64 + tx + 16 * j;
                if (kcol > qrow) wgt = 0.0f;
                Sw[ty * 4 + i][tx + 16 * j] = wgt;
            }
        }
        __syncthreads();

        for (int k = 0; k < 64; ++k) {
            float wv[4], vv[4];
            #pragma unroll
            for (int i = 0; i < 4; ++i) wv[i] = Sw[ty * 4 + i][k];
            #pragma unroll
            for (int j = 0; j < 4; ++j) vv[j] = Vs[k][tx + 16 * j];
            #pragma unroll
            for (int i = 0; i < 4; ++i)
                #pragma unroll
                for (int j = 0; j < 4; ++j)
                    acc[i][j] += wv[i] * vv[j];
        }
    }

    #pragma unroll
    for (int i = 0; i < 4; ++i) {
        const int row = b * SS + qt * 64 + ty * 4 + i;
        #pragma unroll
        for (int j = 0; j < 4; ++j) {
            attnOut[(size_t)row * DD + h * HD + tx + 16 * j] = acc[i][j];
        }
    }
}

// ---------------------------------------------------------------------------
// launch
// ---------------------------------------------------------------------------
extern "C" void kernel_launch(void* const* d_in, const int* in_sizes, int n_in,
                              void* d_out, int out_size, void* d_ws, size_t ws_size,
                              hipStream_t stream) {
    const float* x           = (const float*)d_in[0];
    const float* td          = (const float*)d_in[1];
    // d_in[2] = attn_mask (causal) — implemented via predicate
    const float* uvqk_w      = (const float*)d_in[3];
    const float* uvqk_b      = (const float*)d_in[4];
    const float* gate_w      = (const float*)d_in[5];
    const float* out_w       = (const float*)d_in[6];
    const float* out_b       = (const float*)d_in[7];
    const float* in_norm_w   = (const float*)d_in[8];
    const float* last_norm_w = (const float*)d_in[9];
    const int*   pid         = (const int*)d_in[10];
    float* out = (float*)d_out;
    char*  ws  = (char*)d_ws;

    // workspace layout (~150 MB)
    float* cosT = (float*)ws;                          ws += (size_t)BS * HD * 4;
    float* sinT = (float*)ws;                          ws += (size_t)BS * HD * 4;
    float* h    = (float*)ws;                          ws += (size_t)BS * DD * 4;
    float* uvqk = (float*)ws;                          ws += (size_t)BS * FOURD * 4;
    float* attn = (float*)ws;                          ws += (size_t)BS * DD * 4;
    ushort_t* h_hi  = (ushort_t*)ws;                   ws += (size_t)BS * DD * 2;
    ushort_t* h_lo  = (ushort_t*)ws;                   ws += (size_t)BS * DD * 2;
    ushort_t* g_hi  = (ushort_t*)ws;                   ws += (size_t)BS * DD * 2;
    ushort_t* g_lo  = (ushort_t*)ws;                   ws += (size_t)BS * DD * 2;
    ushort_t* uWt_hi = (ushort_t*)ws;                  ws += (size_t)FOURD * DD * 2;
    ushort_t* uWt_lo = (ushort_t*)ws;                  ws += (size_t)FOURD * DD * 2;
    ushort_t* oWt_hi = (ushort_t*)ws;                  ws += (size_t)DD * DD * 2;
    ushort_t* oWt_lo = (ushort_t*)ws;                  ws += (size_t)DD * DD * 2;
    (void)ws_size;

    rope_table_kernel<<<(BS * 32 + 255) / 256, 256, 0, stream>>>(td, pid, cosT, sinT);
    rmsnorm_kernel<<<BS, 256, 0, stream>>>(x, in_norm_w, nullptr, 0, h, h_hi, h_lo);

    for (int l = 0; l < LL; ++l) {
        // transpose+split this layer's weights
        wsplit_kernel<<<dim3(FOURD / 32, DD / 32), 256, 0, stream>>>(
            uvqk_w + (size_t)l * DD * FOURD, uWt_hi, uWt_lo, DD, FOURD);
        // uvqk = h @ uvqk_w[l] + b
        gemm3_kernel<<<dim3(FOURD / TBN, BS / TBM), 256, 0, stream>>>(
            h_hi, h_lo, uWt_hi, uWt_lo, uvqk_b + (size_t)l * FOURD,
            nullptr, uvqk, nullptr, nullptr, BS, FOURD, DD);
        // u <- silu(u); q,k <- rope
        postproc_kernel<<<BS, 256, 0, stream>>>(uvqk, cosT, sinT);
        // attn
        attn_kernel<<<dim3(SS / 64, HH, BB), 256, 0, stream>>>(uvqk, attn);
        // gated = rmsnorm(attn, gate_w)*u  (+ bf16 split for out GEMM)
        rmsnorm_kernel<<<BS, 256, 0, stream>>>(
            attn, gate_w + (size_t)l * DD, uvqk, FOURD, attn, g_hi, g_lo);
        wsplit_kernel<<<dim3(DD / 32, DD / 32), 256, 0, stream>>>(
            out_w + (size_t)l * DD * DD, oWt_hi, oWt_lo, DD, DD);
        // h = h + gated @ out_w[l] + b   (+ split h for next layer's GEMM)
        gemm3_kernel<<<dim3(DD / TBN, BS / TBM), 256, 0, stream>>>(
            g_hi, g_lo, oWt_hi, oWt_lo, out_b + (size_t)l * DD,
            h, h, h_hi, h_lo, BS, DD, DD);
    }

    rmsnorm_kernel<<<BS, 256, 0, stream>>>(h, last_norm_w, nullptr, 0, out, nullptr, nullptr);
}

// Round 3
// 1865.306 us; speedup vs baseline: 2.6166x; 1.6994x over previous
//
#include <hip/hip_runtime.h>
#include <hip/hip_bf16.h>
#include <math.h>

// Problem constants: B=2, S=2048, D=1024, H=16, HD=64, L=4
#define BB 2
#define SS 2048
#define DD 1024
#define HH 16
#define HD 64
#define LL 4
#define BS (BB * SS)          // 4096 tokens
#define FOURD (4 * DD)        // 4096

typedef unsigned int u32;
typedef unsigned short ushort_t;
typedef __attribute__((ext_vector_type(8))) short bf16x8;
typedef __attribute__((ext_vector_type(4))) float f32x4;

__device__ __forceinline__ float silu_f(float x) {
    return x / (1.0f + expf(-x));
}
__device__ __forceinline__ float silu_fast(float x) {
    return x / (1.0f + __expf(-x));
}

// bf16 round-to-nearest-even split helpers
__device__ __forceinline__ ushort_t f2bf(float x) {
    u32 u = __float_as_uint(x);
    u32 r = (u + 0x7fffu + ((u >> 16) & 1u)) >> 16;
    return (ushort_t)r;
}
__device__ __forceinline__ float bf2f(ushort_t h) {
    return __uint_as_float((u32)h << 16);
}

// async global->LDS, 16B per lane; lds dest = wave-uniform base + lane*16
typedef __attribute__((address_space(3))) u32 lds_u32;
typedef const __attribute__((address_space(1))) u32 glb_u32;
__device__ __forceinline__ void gload16(const void* g, const void* lds) {
    __builtin_amdgcn_global_load_lds((glb_u32*)(uintptr_t)g,
                                     (lds_u32*)(uintptr_t)lds, 16, 0, 0);
}

#define MFMA16(a, b, c) __builtin_amdgcn_mfma_f32_16x16x32_bf16((a), (b), (c), 0, 0, 0)

union U8 { u32 d[4]; bf16x8 v; };

// ---------------------------------------------------------------------------
// RoPE tables: cos/sin [BS][HD]; pos = position_id + 0.1*log(dt+1)
// ---------------------------------------------------------------------------
__global__ __launch_bounds__(256) void rope_table_kernel(
    const float* __restrict__ td, const int* __restrict__ pid,
    float* __restrict__ cosT, float* __restrict__ sinT)
{
    int idx = blockIdx.x * blockDim.x + threadIdx.x;   // over BS*32
    if (idx >= BS * 32) return;
    int i = idx & 31, bs = idx >> 5;
    float pos = (float)pid[bs] + 0.1f * logf(td[bs] + 1.0f);
    float inv = powf(10000.0f, -(float)(2 * i) / 64.0f);
    float f = pos * inv;
    float c = cosf(f), s = sinf(f);
    cosT[bs * HD + i] = c;  cosT[bs * HD + i + 32] = c;
    sinT[bs * HD + i] = s;  sinT[bs * HD + i + 32] = s;
}

// ---------------------------------------------------------------------------
// RMSNorm over D=1024; optional elementwise multiplier; optional bf16 hi/lo
// ---------------------------------------------------------------------------
__global__ __launch_bounds__(256) void rmsnorm_kernel(
    const float* __restrict__ in, const float* __restrict__ w,
    const float* __restrict__ mul, int mulStride,
    float* __restrict__ out,
    ushort_t* __restrict__ hi, ushort_t* __restrict__ lo)
{
    __shared__ float red[4];
    int row = blockIdx.x, t = threadIdx.x;
    const float4 v = *(const float4*)&in[(size_t)row * DD + t * 4];
    float ss = v.x * v.x + v.y * v.y + v.z * v.z + v.w * v.w;
    #pragma unroll
    for (int o = 32; o > 0; o >>= 1) ss += __shfl_down(ss, o);
    if ((t & 63) == 0) red[t >> 6] = ss;
    __syncthreads();
    float tot = red[0] + red[1] + red[2] + red[3];
    float r = rsqrtf(tot * (1.0f / (float)DD) + 1e-6f);
    const float4 wv = *(const float4*)&w[t * 4];
    float4 o4;
    o4.x = v.x * r * wv.x;  o4.y = v.y * r * wv.y;
    o4.z = v.z * r * wv.z;  o4.w = v.w * r * wv.w;
    if (mul) {
        const float4 m = *(const float4*)&mul[(size_t)row * mulStride + t * 4];
        o4.x *= m.x; o4.y *= m.y; o4.z *= m.z; o4.w *= m.w;
    }
    const size_t o = (size_t)row * DD + t * 4;
    *(float4*)&out[o] = o4;
    if (hi) {
        ushort4 h4, l4;
        float e;
        h4.x = f2bf(o4.x); e = o4.x - bf2f(h4.x); l4.x = f2bf(e);
        h4.y = f2bf(o4.y); e = o4.y - bf2f(h4.y); l4.y = f2bf(e);
        h4.z = f2bf(o4.z); e = o4.z - bf2f(h4.z); l4.z = f2bf(e);
        h4.w = f2bf(o4.w); e = o4.w - bf2f(h4.w); l4.w = f2bf(e);
        *(ushort4*)&hi[o] = h4;
        *(ushort4*)&lo[o] = l4;
    }
}

// ---------------------------------------------------------------------------
// Weight transpose + bf16 split: W [K][N] fp32 -> Wt_hi/Wt_lo [N][K] bf16
// ---------------------------------------------------------------------------
__global__ __launch_bounds__(256) void wsplit_kernel(
    const float* __restrict__ W, ushort_t* __restrict__ hi,
    ushort_t* __restrict__ lo, int K, int N)
{
    __shared__ float T[32][33];
    const int n0 = blockIdx.x * 32, k0 = blockIdx.y * 32;
    const int t = threadIdx.x;
    {
        const int r = t >> 3, cg = (t & 7) * 4;
        const float4 v = *(const float4*)&W[(size_t)(k0 + r) * N + n0 + cg];
        T[r][cg] = v.x; T[r][cg + 1] = v.y; T[r][cg + 2] = v.z; T[r][cg + 3] = v.w;
    }
    __syncthreads();
    {
        const int n = t >> 3, kg = (t & 7) * 4;
        ushort4 h4, l4;
        float x, e;
        x = T[kg + 0][n]; h4.x = f2bf(x); e = x - bf2f(h4.x); l4.x = f2bf(e);
        x = T[kg + 1][n]; h4.y = f2bf(x); e = x - bf2f(h4.y); l4.y = f2bf(e);
        x = T[kg + 2][n]; h4.z = f2bf(x); e = x - bf2f(h4.z); l4.z = f2bf(e);
        x = T[kg + 3][n]; h4.w = f2bf(x); e = x - bf2f(h4.w); l4.w = f2bf(e);
        const size_t o = (size_t)(n0 + n) * K + k0 + kg;
        *(ushort4*)&hi[o] = h4;
        *(ushort4*)&lo[o] = l4;
    }
}

// ---------------------------------------------------------------------------
// bf16x3 MFMA GEMM (unchanged from R1)
// ---------------------------------------------------------------------------
#define TBM 128
#define TBN 128
#define TBK 32
__global__ __launch_bounds__(256) void gemm3_kernel(
    const ushort_t* __restrict__ Ah, const ushort_t* __restrict__ Al,
    const ushort_t* __restrict__ Bh, const ushort_t* __restrict__ Bl,
    const float* __restrict__ bias, const float* __restrict__ res,
    float* __restrict__ C, ushort_t* __restrict__ Chi, ushort_t* __restrict__ Clo,
    int M, int N, int K)
{
    __shared__ ushort_t sAh[TBM][TBK];
    __shared__ ushort_t sAl[TBM][TBK];
    __shared__ ushort_t sBh[TBN][TBK];
    __shared__ ushort_t sBl[TBN][TBK];

    const int tid = threadIdx.x;
    const int w = tid >> 6, l = tid & 63;
    const int wr = w >> 1, wc = w & 1;
    const int m0 = blockIdx.y * TBM, n0 = blockIdx.x * TBN;
    const int lr = l & 15, lk = (l >> 4) * 8;

    f32x4 acc[4][4];
    #pragma unroll
    for (int m = 0; m < 4; ++m)
        #pragma unroll
        for (int n = 0; n < 4; ++n)
            acc[m][n] = (f32x4){0.f, 0.f, 0.f, 0.f};

    for (int k0 = 0; k0 < K; k0 += TBK) {
        if (k0) __syncthreads();
        #pragma unroll
        for (int i = 0; i < 2; ++i) {
            const int cb = i * 256 + w * 64;
            const int chunk = cb + l;
            const int row = chunk >> 2;
            const int kc = (chunk & 3) * 8;
            const size_t ga = (size_t)(m0 + row) * K + k0 + kc;
            const size_t gb = (size_t)(n0 + row) * K + k0 + kc;
            gload16(Ah + ga, &sAh[0][0] + (size_t)cb * 8);
            gload16(Al + ga, &sAl[0][0] + (size_t)cb * 8);
            gload16(Bh + gb, &sBh[0][0] + (size_t)cb * 8);
            gload16(Bl + gb, &sBl[0][0] + (size_t)cb * 8);
        }
        __syncthreads();

        bf16x8 ah[4], al[4], bh[4], bl[4];
        #pragma unroll
        for (int m = 0; m < 4; ++m) {
            ah[m] = *(const bf16x8*)&sAh[wr * 64 + m * 16 + lr][lk];
            al[m] = *(const bf16x8*)&sAl[wr * 64 + m * 16 + lr][lk];
        }
        #pragma unroll
        for (int n = 0; n < 4; ++n) {
            bh[n] = *(const bf16x8*)&sBh[wc * 64 + n * 16 + lr][lk];
            bl[n] = *(const bf16x8*)&sBl[wc * 64 + n * 16 + lr][lk];
        }
        #pragma unroll
        for (int m = 0; m < 4; ++m) {
            #pragma unroll
            for (int n = 0; n < 4; ++n) {
                acc[m][n] = MFMA16(ah[m], bh[n], acc[m][n]);
                acc[m][n] = MFMA16(al[m], bh[n], acc[m][n]);
                acc[m][n] = MFMA16(ah[m], bl[n], acc[m][n]);
            }
        }
    }

    #pragma unroll
    for (int m = 0; m < 4; ++m) {
        #pragma unroll
        for (int n = 0; n < 4; ++n) {
            const int col = n0 + wc * 64 + n * 16 + lr;
            #pragma unroll
            for (int r = 0; r < 4; ++r) {
                const int row = m0 + wr * 64 + m * 16 + (l >> 4) * 4 + r;
                const size_t o = (size_t)row * N + col;
                float v = acc[m][n][r] + bias[col];
                if (res) v += res[o];
                C[o] = v;
                if (Chi) {
                    ushort_t hv = f2bf(v);
                    Chi[o] = hv;
                    Clo[o] = f2bf(v - bf2f(hv));
                }
            }
        }
    }
}

// ---------------------------------------------------------------------------
// Post-process: u <- silu(u) in place; q,k <- RoPE -> head-major bf16 hi/lo
// [b][h][s][64]; v -> bf16 hi/lo transposed [b][h][d][s].
// ---------------------------------------------------------------------------
__global__ __launch_bounds__(256) void postproc_kernel(
    float* __restrict__ uvqk,
    const float* __restrict__ cosT, const float* __restrict__ sinT,
    ushort_t* __restrict__ q_hi, ushort_t* __restrict__ q_lo,
    ushort_t* __restrict__ k_hi, ushort_t* __restrict__ k_lo,
    ushort_t* __restrict__ vT_hi, ushort_t* __restrict__ vT_lo)
{
    const int bs = blockIdx.x, t = threadIdx.x;
    const int b = bs >> 11, s = bs & (SS - 1);
    float* base = uvqk + (size_t)bs * FOURD;

    float4 u = *(float4*)&base[t * 4];
    u.x = silu_f(u.x); u.y = silu_f(u.y); u.z = silu_f(u.z); u.w = silu_f(u.w);
    *(float4*)&base[t * 4] = u;

    const int hh = t >> 4, p = (t & 15) * 2;
    const float c0 = cosT[bs * HD + p], c1 = cosT[bs * HD + p + 1];
    const float s0 = sinT[bs * HD + p], s1 = sinT[bs * HD + p + 1];
    const size_t hrow = ((size_t)(b * HH + hh) * SS + s) * HD;
    #pragma unroll
    for (int sect = 2; sect <= 3; ++sect) {
        const float* qp = base + sect * DD + hh * HD;
        const float a0 = qp[p], a1 = qp[p + 1];
        const float b0 = qp[p + 32], b1 = qp[p + 33];
        float o0 = a0 * c0 - b0 * s0;
        float o1 = a1 * c1 - b1 * s1;
        float o2 = b0 * c0 + a0 * s0;
        float o3 = b1 * c1 + a1 * s1;
        ushort_t* dh = (sect == 2) ? q_hi : k_hi;
        ushort_t* dl = (sect == 2) ? q_lo : k_lo;
        ushort_t hv;
        hv = f2bf(o0); dh[hrow + p]      = hv; dl[hrow + p]      = f2bf(o0 - bf2f(hv));
        hv = f2bf(o1); dh[hrow + p + 1]  = hv; dl[hrow + p + 1]  = f2bf(o1 - bf2f(hv));
        hv = f2bf(o2); dh[hrow + p + 32] = hv; dl[hrow + p + 32] = f2bf(o2 - bf2f(hv));
        hv = f2bf(o3); dh[hrow + p + 33] = hv; dl[hrow + p + 33] = f2bf(o3 - bf2f(hv));
    }

    {
        const int dg = t * 4;
        const int hv_ = dg >> 6;
        const float4 v4 = *(const float4*)&base[DD + dg];
        const size_t vbase = ((size_t)(b * HH + hv_) * HD + (dg & 63)) * SS + s;
        float vv[4] = {v4.x, v4.y, v4.z, v4.w};
        #pragma unroll
        for (int i = 0; i < 4; ++i) {
            ushort_t hh2 = f2bf(vv[i]);
            vT_hi[vbase + (size_t)i * SS] = hh2;
            vT_lo[vbase + (size_t)i * SS] = f2bf(vv[i] - bf2f(hh2));
        }
    }
}

// ---------------------------------------------------------------------------
// MFMA causal SiLU attention. Block: 128 q-rows x (b,h); 4 waves x 32 rows.
// ---------------------------------------------------------------------------
__global__ __launch_bounds__(256) void attn_kernel(
    const ushort_t* __restrict__ q_hi, const ushort_t* __restrict__ q_lo,
    const ushort_t* __restrict__ k_hi, const ushort_t* __restrict__ k_lo,
    const ushort_t* __restrict__ vT_hi, const ushort_t* __restrict__ vT_lo,
    float* __restrict__ attnOut)
{
    __shared__ ushort_t sKh[64 * 64];
    __shared__ ushort_t sKl[64 * 64];
    __shared__ ushort_t sVh[64 * 64];
    __shared__ ushort_t sVl[64 * 64];

    const int qt = (SS / 128 - 1) - blockIdx.x;     // heavy tiles first
    const int h = blockIdx.y, b = blockIdx.z;
    const int tid = threadIdx.x;
    const int w = tid >> 6, l = tid & 63;
    const int lr = l & 15, g = l >> 4;

    const size_t headQ = ((size_t)(b * HH + h) * SS) * HD;
    const size_t headV = ((size_t)(b * HH + h) * HD) * SS;

    bf16x8 qh[2][2], ql[2][2];
    {
        const int qrow0 = qt * 128 + w * 32;
        #pragma unroll
        for (int qf = 0; qf < 2; ++qf)
            #pragma unroll
            for (int ds_ = 0; ds_ < 2; ++ds_) {
                const size_t off = headQ + (size_t)(qrow0 + qf * 16 + lr) * HD
                                   + ds_ * 32 + g * 8;
                qh[qf][ds_] = *(const bf16x8*)&q_hi[off];
                ql[qf][ds_] = *(const bf16x8*)&q_lo[off];
            }
    }

    f32x4 acc[2][4];
    #pragma unroll
    for (int qf = 0; qf < 2; ++qf)
        #pragma unroll
        for (int df = 0; df < 4; ++df)
            acc[qf][df] = (f32x4){0.f, 0.f, 0.f, 0.f};

    const int nkt = 2 * qt + 2;
    for (int kt = 0; kt < nkt; ++kt) {
        __syncthreads();
        {
            const ushort_t* kbh = k_hi + headQ + (size_t)kt * 64 * HD;
            const ushort_t* kbl = k_lo + headQ + (size_t)kt * 64 * HD;
            const ushort_t* vbh = vT_hi + headV + kt * 64;
            const ushort_t* vbl = vT_lo + headV + kt * 64;
            #pragma unroll
            for (int rep = 0; rep < 2; ++rep) {
                const int cb = rep * 256 + w * 64;     // wave-uniform
                const int chunk = cb + l;
                const int row = chunk >> 3, dblk = chunk & 7;
                const int sblk = dblk ^ (row & 7);
                gload16(kbh + (size_t)row * HD + sblk * 8, sKh + (size_t)cb * 8);
                gload16(kbl + (size_t)row * HD + sblk * 8, sKl + (size_t)cb * 8);
                gload16(vbh + (size_t)row * SS + sblk * 8, sVh + (size_t)cb * 8);
                gload16(vbl + (size_t)row * SS + sblk * 8, sVl + (size_t)cb * 8);
            }
        }
        __syncthreads();

        f32x4 sc[4][2];
        #pragma unroll
        for (int f = 0; f < 4; ++f)
            #pragma unroll
            for (int qf = 0; qf < 2; ++qf)
                sc[f][qf] = (f32x4){0.f, 0.f, 0.f, 0.f};

        #pragma unroll
        for (int ds_ = 0; ds_ < 2; ++ds_) {
            bf16x8 kh[4], kl[4];
            #pragma unroll
            for (int f = 0; f < 4; ++f) {
                const int addr = (16 * f + lr) * 64 + (((4 * ds_ + g) ^ (lr & 7)) * 8);
                kh[f] = *(const bf16x8*)&sKh[addr];
                kl[f] = *(const bf16x8*)&sKl[addr];
            }
            #pragma unroll
            for (int f = 0; f < 4; ++f)
                #pragma unroll
                for (int qf = 0; qf < 2; ++qf) {
                    sc[f][qf] = MFMA16(kh[f], qh[qf][ds_], sc[f][qf]);
                    sc[f][qf] = MFMA16(kl[f], qh[qf][ds_], sc[f][qf]);
                    sc[f][qf] = MFMA16(kh[f], ql[qf][ds_], sc[f][qf]);
                }
        }

        u32 pkh[4][2][2], pkl[4][2][2];
        #pragma unroll
        for (int f = 0; f < 4; ++f) {
            #pragma unroll
            for (int qf = 0; qf < 2; ++qf) {
                const int qrow = qt * 128 + w * 32 + qf * 16 + lr;
                float pv[4];
                #pragma unroll
                for (int r = 0; r < 4; ++r) {
                    const int key = kt * 64 + 16 * f + 4 * g + r;
                    const float x = sc[f][qf][r] * 0.125f;
                    pv[r] = (key <= qrow) ? silu_fast(x) : 0.0f;
                }
                #pragma unroll
                for (int t2 = 0; t2 < 2; ++t2) {
                    const ushort_t h0 = f2bf(pv[2 * t2]);
                    const ushort_t h1 = f2bf(pv[2 * t2 + 1]);
                    pkh[f][qf][t2] = (u32)h0 | ((u32)h1 << 16);
                    const float l0 = pv[2 * t2] - bf2f(h0);
                    const float l1 = pv[2 * t2 + 1] - bf2f(h1);
                    pkl[f][qf][t2] = (u32)f2bf(l0) | ((u32)f2bf(l1) << 16);
                }
            }
        }

        #pragma unroll
        for (int s2 = 0; s2 < 2; ++s2) {
            U8 ah[2], al[2];
            #pragma unroll
            for (int qf = 0; qf < 2; ++qf) {
                #pragma unroll
                for (int d = 0; d < 4; ++d) {
                    const int srcLane = lr + 16 * (2 * (g & 1) + (d >> 1));
                    const int t2 = d & 1;
                    int x0 = __shfl((int)pkh[2 * s2][qf][t2], srcLane, 64);
                    int x1 = __shfl((int)pkh[2 * s2 + 1][qf][t2], srcLane, 64);
                    ah[qf].d[d] = (g & 2) ? x1 : x0;
                    x0 = __shfl((int)pkl[2 * s2][qf][t2], srcLane, 64);
                    x1 = __shfl((int)pkl[2 * s2 + 1][qf][t2], srcLane, 64);
                    al[qf].d[d] = (g & 2) ? x1 : x0;
                }
            }
            #pragma unroll
            for (int df = 0; df < 4; ++df) {
                const int vaddr = (16 * df + lr) * 64 + (((4 * s2 + g) ^ (lr & 7)) * 8);
                const bf16x8 vh = *(const bf16x8*)&sVh[vaddr];
                const bf16x8 vl = *(const bf16x8*)&sVl[vaddr];
                #pragma unroll
                for (int qf = 0; qf < 2; ++qf) {
                    acc[qf][df] = MFMA16(ah[qf].v, vh, acc[qf][df]);
                    acc[qf][df] = MFMA16(al[qf].v, vh, acc[qf][df]);
                    acc[qf][df] = MFMA16(ah[qf].v, vl, acc[qf][df]);
                }
            }
        }
    }

    #pragma unroll
    for (int qf = 0; qf < 2; ++qf) {
        #pragma unroll
        for (int df = 0; df < 4; ++df) {
            #pragma unroll
            for (int r = 0; r < 4; ++r) {
                const int row = qt * 128 + w * 32 + qf * 16 + 4 * g + r;
                attnOut[(size_t)(b * SS + row) * DD + h * HD + 16 * df + lr]
                    = acc[qf][df][r];
            }
        }
    }
}

// ---------------------------------------------------------------------------
// launch
// ---------------------------------------------------------------------------
extern "C" void kernel_launch(void* const* d_in, const int* in_sizes, int n_in,
                              void* d_out, int out_size, void* d_ws, size_t ws_size,
                              hipStream_t stream) {
    const float* x           = (const float*)d_in[0];
    const float* td          = (const float*)d_in[1];
    const float* uvqk_w      = (const float*)d_in[3];
    const float* uvqk_b      = (const float*)d_in[4];
    const float* gate_w      = (const float*)d_in[5];
    const float* out_w       = (const float*)d_in[6];
    const float* out_b       = (const float*)d_in[7];
    const float* in_norm_w   = (const float*)d_in[8];
    const float* last_norm_w = (const float*)d_in[9];
    const int*   pid         = (const int*)d_in[10];
    float* out = (float*)d_out;
    char*  ws  = (char*)d_ws;

    const size_t QKV = (size_t)BB * HH * SS * HD;      // 4.19M elems

    float* cosT = (float*)ws;                          ws += (size_t)BS * HD * 4;
    float* sinT = (float*)ws;                          ws += (size_t)BS * HD * 4;
    float* h    = (float*)ws;                          ws += (size_t)BS * DD * 4;
    float* uvqk = (float*)ws;                          ws += (size_t)BS * FOURD * 4;
    float* attn = (float*)ws;                          ws += (size_t)BS * DD * 4;
    ushort_t* h_hi  = (ushort_t*)ws;                   ws += (size_t)BS * DD * 2;
    ushort_t* h_lo  = (ushort_t*)ws;                   ws += (size_t)BS * DD * 2;
    ushort_t* g_hi  = (ushort_t*)ws;                   ws += (size_t)BS * DD * 2;
    ushort_t* g_lo  = (ushort_t*)ws;                   ws += (size_t)BS * DD * 2;
    ushort_t* uWt_hi = (ushort_t*)ws;                  ws += (size_t)FOURD * DD * 2;
    ushort_t* uWt_lo = (ushort_t*)ws;                  ws += (size_t)FOURD * DD * 2;
    ushort_t* oWt_hi = (ushort_t*)ws;                  ws += (size_t)DD * DD * 2;
    ushort_t* oWt_lo = (ushort_t*)ws;                  ws += (size_t)DD * DD * 2;
    ushort_t* q_hi  = (ushort_t*)ws;                   ws += QKV * 2;
    ushort_t* q_lo  = (ushort_t*)ws;                   ws += QKV * 2;
    ushort_t* k_hi  = (ushort_t*)ws;                   ws += QKV * 2;
    ushort_t* k_lo  = (ushort_t*)ws;                   ws += QKV * 2;
    ushort_t* vT_hi = (ushort_t*)ws;                   ws += QKV * 2;
    ushort_t* vT_lo = (ushort_t*)ws;                   ws += QKV * 2;
    (void)ws_size;

    rope_table_kernel<<<(BS * 32 + 255) / 256, 256, 0, stream>>>(td, pid, cosT, sinT);
    rmsnorm_kernel<<<BS, 256, 0, stream>>>(x, in_norm_w, nullptr, 0, h, h_hi, h_lo);

    for (int l = 0; l < LL; ++l) {
        wsplit_kernel<<<dim3(FOURD / 32, DD / 32), 256, 0, stream>>>(
            uvqk_w + (size_t)l * DD * FOURD, uWt_hi, uWt_lo, DD, FOURD);
        gemm3_kernel<<<dim3(FOURD / TBN, BS / TBM), 256, 0, stream>>>(
            h_hi, h_lo, uWt_hi, uWt_lo, uvqk_b + (size_t)l * FOURD,
            nullptr, uvqk, nullptr, nullptr, BS, FOURD, DD);
        postproc_kernel<<<BS, 256, 0, stream>>>(
            uvqk, cosT, sinT, q_hi, q_lo, k_hi, k_lo, vT_hi, vT_lo);
        attn_kernel<<<dim3(SS / 128, HH, BB), 256, 0, stream>>>(
            q_hi, q_lo, k_hi, k_lo, vT_hi, vT_lo, attn);
        rmsnorm_kernel<<<BS, 256, 0, stream>>>(
            attn, gate_w + (size_t)l * DD, uvqk, FOURD, attn, g_hi, g_lo);
        wsplit_kernel<<<dim3(DD / 32, DD / 32), 256, 0, stream>>>(
            out_w + (size_t)l * DD * DD, oWt_hi, oWt_lo, DD, DD);
        gemm3_kernel<<<dim3(DD / TBN, BS / TBM), 256, 0, stream>>>(
            g_hi, g_lo, oWt_hi, oWt_lo, out_b + (size_t)l * DD,
            h, h, h_hi, h_lo, BS, DD, DD);
    }

    rmsnorm_kernel<<<BS, 256, 0, stream>>>(h, last_norm_w, nullptr, 0, out, nullptr, nullptr);
}

// Round 5
// 1667.417 us; speedup vs baseline: 2.9271x; 1.1187x over previous
//
#include <hip/hip_runtime.h>
#include <hip/hip_bf16.h>
#include <math.h>

// Problem constants: B=2, S=2048, D=1024, H=16, HD=64, L=4
#define BB 2
#define SS 2048
#define DD 1024
#define HH 16
#define HD 64
#define LL 4
#define BS (BB * SS)          // 4096 tokens
#define FOURD (4 * DD)        // 4096

typedef unsigned int u32;
typedef unsigned short ushort_t;
typedef __attribute__((ext_vector_type(8))) short bf16x8;
typedef __attribute__((ext_vector_type(4))) float f32x4;

__device__ __forceinline__ float silu_f(float x) {
    return x / (1.0f + expf(-x));
}
__device__ __forceinline__ float silu_fast(float x) {
    return x / (1.0f + __expf(-x));
}

// bf16 round-to-nearest-even split helpers
__device__ __forceinline__ ushort_t f2bf(float x) {
    u32 u = __float_as_uint(x);
    u32 r = (u + 0x7fffu + ((u >> 16) & 1u)) >> 16;
    return (ushort_t)r;
}
__device__ __forceinline__ float bf2f(ushort_t h) {
    return __uint_as_float((u32)h << 16);
}

// async global->LDS, 16B per lane; lds dest = wave-uniform base + lane*16
typedef __attribute__((address_space(3))) u32 lds_u32;
typedef const __attribute__((address_space(1))) u32 glb_u32;
__device__ __forceinline__ void gload16(const void* g, const void* lds) {
    __builtin_amdgcn_global_load_lds((glb_u32*)(uintptr_t)g,
                                     (lds_u32*)(uintptr_t)lds, 16, 0, 0);
}

#define MFMA16(a, b, c) __builtin_amdgcn_mfma_f32_16x16x32_bf16((a), (b), (c), 0, 0, 0)

union U8 { u32 d[4]; bf16x8 v; };

// ---------------------------------------------------------------------------
// RoPE tables: cos/sin [BS][HD]; pos = position_id + 0.1*log(dt+1)
// ---------------------------------------------------------------------------
__global__ __launch_bounds__(256) void rope_table_kernel(
    const float* __restrict__ td, const int* __restrict__ pid,
    float* __restrict__ cosT, float* __restrict__ sinT)
{
    int idx = blockIdx.x * blockDim.x + threadIdx.x;   // over BS*32
    if (idx >= BS * 32) return;
    int i = idx & 31, bs = idx >> 5;
    float pos = (float)pid[bs] + 0.1f * logf(td[bs] + 1.0f);
    float inv = powf(10000.0f, -(float)(2 * i) / 64.0f);
    float f = pos * inv;
    float c = cosf(f), s = sinf(f);
    cosT[bs * HD + i] = c;  cosT[bs * HD + i + 32] = c;
    sinT[bs * HD + i] = s;  sinT[bs * HD + i + 32] = s;
}

// ---------------------------------------------------------------------------
// RMSNorm over D=1024; optional elementwise multiplier; optional bf16 hi/lo
// ---------------------------------------------------------------------------
__global__ __launch_bounds__(256) void rmsnorm_kernel(
    const float* __restrict__ in, const float* __restrict__ w,
    const float* __restrict__ mul, int mulStride,
    float* __restrict__ out,
    ushort_t* __restrict__ hi, ushort_t* __restrict__ lo)
{
    __shared__ float red[4];
    int row = blockIdx.x, t = threadIdx.x;
    const float4 v = *(const float4*)&in[(size_t)row * DD + t * 4];
    float ss = v.x * v.x + v.y * v.y + v.z * v.z + v.w * v.w;
    #pragma unroll
    for (int o = 32; o > 0; o >>= 1) ss += __shfl_down(ss, o);
    if ((t & 63) == 0) red[t >> 6] = ss;
    __syncthreads();
    float tot = red[0] + red[1] + red[2] + red[3];
    float r = rsqrtf(tot * (1.0f / (float)DD) + 1e-6f);
    const float4 wv = *(const float4*)&w[t * 4];
    float4 o4;
    o4.x = v.x * r * wv.x;  o4.y = v.y * r * wv.y;
    o4.z = v.z * r * wv.z;  o4.w = v.w * r * wv.w;
    if (mul) {
        const float4 m = *(const float4*)&mul[(size_t)row * mulStride + t * 4];
        o4.x *= m.x; o4.y *= m.y; o4.z *= m.z; o4.w *= m.w;
    }
    const size_t o = (size_t)row * DD + t * 4;
    *(float4*)&out[o] = o4;
    if (hi) {
        ushort4 h4, l4;
        float e;
        h4.x = f2bf(o4.x); e = o4.x - bf2f(h4.x); l4.x = f2bf(e);
        h4.y = f2bf(o4.y); e = o4.y - bf2f(h4.y); l4.y = f2bf(e);
        h4.z = f2bf(o4.z); e = o4.z - bf2f(h4.z); l4.z = f2bf(e);
        h4.w = f2bf(o4.w); e = o4.w - bf2f(h4.w); l4.w = f2bf(e);
        *(ushort4*)&hi[o] = h4;
        *(ushort4*)&lo[o] = l4;
    }
}

// ---------------------------------------------------------------------------
// Weight transpose + bf16 split: W [K][N] fp32 -> Wt_hi/Wt_lo [N][K] bf16
// ---------------------------------------------------------------------------
__global__ __launch_bounds__(256) void wsplit_kernel(
    const float* __restrict__ W, ushort_t* __restrict__ hi,
    ushort_t* __restrict__ lo, int K, int N)
{
    __shared__ float T[32][33];
    const int n0 = blockIdx.x * 32, k0 = blockIdx.y * 32;
    const int t = threadIdx.x;
    {
        const int r = t >> 3, cg = (t & 7) * 4;
        const float4 v = *(const float4*)&W[(size_t)(k0 + r) * N + n0 + cg];
        T[r][cg] = v.x; T[r][cg + 1] = v.y; T[r][cg + 2] = v.z; T[r][cg + 3] = v.w;
    }
    __syncthreads();
    {
        const int n = t >> 3, kg = (t & 7) * 4;
        ushort4 h4, l4;
        float x, e;
        x = T[kg + 0][n]; h4.x = f2bf(x); e = x - bf2f(h4.x); l4.x = f2bf(e);
        x = T[kg + 1][n]; h4.y = f2bf(x); e = x - bf2f(h4.y); l4.y = f2bf(e);
        x = T[kg + 2][n]; h4.z = f2bf(x); e = x - bf2f(h4.z); l4.z = f2bf(e);
        x = T[kg + 3][n]; h4.w = f2bf(x); e = x - bf2f(h4.w); l4.w = f2bf(e);
        const size_t o = (size_t)(n0 + n) * K + k0 + kg;
        *(ushort4*)&hi[o] = h4;
        *(ushort4*)&lo[o] = l4;
    }
}

// ---------------------------------------------------------------------------
// bf16x3 MFMA GEMM (unchanged)
// ---------------------------------------------------------------------------
#define TBM 128
#define TBN 128
#define TBK 32
__global__ __launch_bounds__(256) void gemm3_kernel(
    const ushort_t* __restrict__ Ah, const ushort_t* __restrict__ Al,
    const ushort_t* __restrict__ Bh, const ushort_t* __restrict__ Bl,
    const float* __restrict__ bias, const float* __restrict__ res,
    float* __restrict__ C, ushort_t* __restrict__ Chi, ushort_t* __restrict__ Clo,
    int M, int N, int K)
{
    __shared__ ushort_t sAh[TBM][TBK];
    __shared__ ushort_t sAl[TBM][TBK];
    __shared__ ushort_t sBh[TBN][TBK];
    __shared__ ushort_t sBl[TBN][TBK];

    const int tid = threadIdx.x;
    const int w = tid >> 6, l = tid & 63;
    const int wr = w >> 1, wc = w & 1;
    const int m0 = blockIdx.y * TBM, n0 = blockIdx.x * TBN;
    const int lr = l & 15, lk = (l >> 4) * 8;

    f32x4 acc[4][4];
    #pragma unroll
    for (int m = 0; m < 4; ++m)
        #pragma unroll
        for (int n = 0; n < 4; ++n)
            acc[m][n] = (f32x4){0.f, 0.f, 0.f, 0.f};

    for (int k0 = 0; k0 < K; k0 += TBK) {
        if (k0) __syncthreads();
        #pragma unroll
        for (int i = 0; i < 2; ++i) {
            const int cb = i * 256 + w * 64;
            const int chunk = cb + l;
            const int row = chunk >> 2;
            const int kc = (chunk & 3) * 8;
            const size_t ga = (size_t)(m0 + row) * K + k0 + kc;
            const size_t gb = (size_t)(n0 + row) * K + k0 + kc;
            gload16(Ah + ga, &sAh[0][0] + (size_t)cb * 8);
            gload16(Al + ga, &sAl[0][0] + (size_t)cb * 8);
            gload16(Bh + gb, &sBh[0][0] + (size_t)cb * 8);
            gload16(Bl + gb, &sBl[0][0] + (size_t)cb * 8);
        }
        __syncthreads();

        bf16x8 ah[4], al[4], bh[4], bl[4];
        #pragma unroll
        for (int m = 0; m < 4; ++m) {
            ah[m] = *(const bf16x8*)&sAh[wr * 64 + m * 16 + lr][lk];
            al[m] = *(const bf16x8*)&sAl[wr * 64 + m * 16 + lr][lk];
        }
        #pragma unroll
        for (int n = 0; n < 4; ++n) {
            bh[n] = *(const bf16x8*)&sBh[wc * 64 + n * 16 + lr][lk];
            bl[n] = *(const bf16x8*)&sBl[wc * 64 + n * 16 + lr][lk];
        }
        #pragma unroll
        for (int m = 0; m < 4; ++m) {
            #pragma unroll
            for (int n = 0; n < 4; ++n) {
                acc[m][n] = MFMA16(ah[m], bh[n], acc[m][n]);
                acc[m][n] = MFMA16(al[m], bh[n], acc[m][n]);
                acc[m][n] = MFMA16(ah[m], bl[n], acc[m][n]);
            }
        }
    }

    #pragma unroll
    for (int m = 0; m < 4; ++m) {
        #pragma unroll
        for (int n = 0; n < 4; ++n) {
            const int col = n0 + wc * 64 + n * 16 + lr;
            #pragma unroll
            for (int r = 0; r < 4; ++r) {
                const int row = m0 + wr * 64 + m * 16 + (l >> 4) * 4 + r;
                const size_t o = (size_t)row * N + col;
                float v = acc[m][n][r] + bias[col];
                if (res) v += res[o];
                C[o] = v;
                if (Chi) {
                    ushort_t hv = f2bf(v);
                    Chi[o] = hv;
                    Clo[o] = f2bf(v - bf2f(hv));
                }
            }
        }
    }
}

// ---------------------------------------------------------------------------
// Post-process: u <- silu(u) in place; q,k <- RoPE -> head-major bf16 hi/lo
// [b][h][s][64].  (V handled by vtrans_kernel.)
// ---------------------------------------------------------------------------
__global__ __launch_bounds__(256) void postproc_kernel(
    float* __restrict__ uvqk,
    const float* __restrict__ cosT, const float* __restrict__ sinT,
    ushort_t* __restrict__ q_hi, ushort_t* __restrict__ q_lo,
    ushort_t* __restrict__ k_hi, ushort_t* __restrict__ k_lo)
{
    const int bs = blockIdx.x, t = threadIdx.x;
    const int b = bs >> 11, s = bs & (SS - 1);
    float* base = uvqk + (size_t)bs * FOURD;

    float4 u = *(float4*)&base[t * 4];
    u.x = silu_f(u.x); u.y = silu_f(u.y); u.z = silu_f(u.z); u.w = silu_f(u.w);
    *(float4*)&base[t * 4] = u;

    const int hh = t >> 4, p = (t & 15) * 2;
    const float c0 = cosT[bs * HD + p], c1 = cosT[bs * HD + p + 1];
    const float s0 = sinT[bs * HD + p], s1 = sinT[bs * HD + p + 1];
    const size_t hrow = ((size_t)(b * HH + hh) * SS + s) * HD;
    #pragma unroll
    for (int sect = 2; sect <= 3; ++sect) {
        const float* qp = base + sect * DD + hh * HD;
        const float a0 = qp[p], a1 = qp[p + 1];
        const float b0 = qp[p + 32], b1 = qp[p + 33];
        float o0 = a0 * c0 - b0 * s0;
        float o1 = a1 * c1 - b1 * s1;
        float o2 = b0 * c0 + a0 * s0;
        float o3 = b1 * c1 + a1 * s1;
        ushort_t* dh = (sect == 2) ? q_hi : k_hi;
        ushort_t* dl = (sect == 2) ? q_lo : k_lo;
        ushort_t hv;
        hv = f2bf(o0); dh[hrow + p]      = hv; dl[hrow + p]      = f2bf(o0 - bf2f(hv));
        hv = f2bf(o1); dh[hrow + p + 1]  = hv; dl[hrow + p + 1]  = f2bf(o1 - bf2f(hv));
        hv = f2bf(o2); dh[hrow + p + 32] = hv; dl[hrow + p + 32] = f2bf(o2 - bf2f(hv));
        hv = f2bf(o3); dh[hrow + p + 33] = hv; dl[hrow + p + 33] = f2bf(o3 - bf2f(hv));
    }
}

// ---------------------------------------------------------------------------
// V transpose + split: v slice of uvqk -> vT_hi/lo [b][h][d][s], coalesced.
// grid (S/64, H, B); block stages v[64 s][64 d] fp32 in LDS.
// ---------------------------------------------------------------------------
__global__ __launch_bounds__(256) void vtrans_kernel(
    const float* __restrict__ uvqk,
    ushort_t* __restrict__ vT_hi, ushort_t* __restrict__ vT_lo)
{
    __shared__ float T[64][65];
    const int sb = blockIdx.x, h = blockIdx.y, b = blockIdx.z;
    const int t = threadIdx.x;
    const int s0 = sb * 64;
    #pragma unroll
    for (int it = 0; it < 4; ++it) {
        const int idx = it * 256 + t;          // 0..1023
        const int row = idx >> 4, c4 = (idx & 15) * 4;
        const float4 v = *(const float4*)&uvqk[
            (size_t)(b * SS + s0 + row) * FOURD + DD + h * HD + c4];
        T[row][c4] = v.x; T[row][c4 + 1] = v.y;
        T[row][c4 + 2] = v.z; T[row][c4 + 3] = v.w;
    }
    __syncthreads();
    // thread: d = t>>2, 16 s-values starting at (t&3)*16
    const int d = t >> 2, sc = (t & 3) * 16;
    u32 hw[8], lw[8];
    #pragma unroll
    for (int j = 0; j < 8; ++j) {
        const float x0 = T[sc + 2 * j][d];
        const float x1 = T[sc + 2 * j + 1][d];
        const ushort_t h0 = f2bf(x0), h1 = f2bf(x1);
        hw[j] = (u32)h0 | ((u32)h1 << 16);
        lw[j] = (u32)f2bf(x0 - bf2f(h0)) | ((u32)f2bf(x1 - bf2f(h1)) << 16);
    }
    const size_t o = ((size_t)(b * HH + h) * HD + d) * SS + s0 + sc;
    *(uint4*)&vT_hi[o] = make_uint4(hw[0], hw[1], hw[2], hw[3]);
    *(uint4*)&vT_hi[o + 8] = make_uint4(hw[4], hw[5], hw[6], hw[7]);
    *(uint4*)&vT_lo[o] = make_uint4(lw[0], lw[1], lw[2], lw[3]);
    *(uint4*)&vT_lo[o + 8] = make_uint4(lw[4], lw[5], lw[6], lw[7]);
}

// ---------------------------------------------------------------------------
// MFMA causal SiLU attention. Block: 128 q-rows x (b,h); 4 waves x 32 rows.
// Double-buffered K/V staging: stage(kt+1) issued before compute(kt),
// single barrier per k-tile (its implicit vmcnt(0) drain hides under compute).
// ---------------------------------------------------------------------------
__global__ __launch_bounds__(256) void attn_kernel(
    const ushort_t* __restrict__ q_hi, const ushort_t* __restrict__ q_lo,
    const ushort_t* __restrict__ k_hi, const ushort_t* __restrict__ k_lo,
    const ushort_t* __restrict__ vT_hi, const ushort_t* __restrict__ vT_lo,
    float* __restrict__ attnOut)
{
    __shared__ ushort_t sKh[2][64 * 64];
    __shared__ ushort_t sKl[2][64 * 64];
    __shared__ ushort_t sVh[2][64 * 64];
    __shared__ ushort_t sVl[2][64 * 64];

    const int qt = (SS / 128 - 1) - blockIdx.x;     // heavy tiles first
    const int h = blockIdx.y, b = blockIdx.z;
    const int tid = threadIdx.x;
    const int w = tid >> 6, l = tid & 63;
    const int lr = l & 15, g = l >> 4;

    const size_t headQ = ((size_t)(b * HH + h) * SS) * HD;
    const size_t headV = ((size_t)(b * HH + h) * HD) * SS;

    bf16x8 qh[2][2], ql[2][2];
    {
        const int qrow0 = qt * 128 + w * 32;
        #pragma unroll
        for (int qf = 0; qf < 2; ++qf)
            #pragma unroll
            for (int ds_ = 0; ds_ < 2; ++ds_) {
                const size_t off = headQ + (size_t)(qrow0 + qf * 16 + lr) * HD
                                   + ds_ * 32 + g * 8;
                qh[qf][ds_] = *(const bf16x8*)&q_hi[off];
                ql[qf][ds_] = *(const bf16x8*)&q_lo[off];
            }
    }

    f32x4 acc[2][4];
    #pragma unroll
    for (int qf = 0; qf < 2; ++qf)
        #pragma unroll
        for (int df = 0; df < 4; ++df)
            acc[qf][df] = (f32x4){0.f, 0.f, 0.f, 0.f};

    const int nkt = 2 * qt + 2;

    // staging helper (macro to keep gload size literal)
#define STAGE_TILE(pb, kt_)                                                    \
    {                                                                          \
        const ushort_t* kbh = k_hi + headQ + (size_t)(kt_) * 64 * HD;          \
        const ushort_t* kbl = k_lo + headQ + (size_t)(kt_) * 64 * HD;          \
        const ushort_t* vbh = vT_hi + headV + (kt_) * 64;                      \
        const ushort_t* vbl = vT_lo + headV + (kt_) * 64;                      \
        _Pragma("unroll")                                                      \
        for (int rep = 0; rep < 2; ++rep) {                                    \
            const int cb = rep * 256 + w * 64;                                 \
            const int chunk = cb + l;                                          \
            const int row = chunk >> 3, dblk = chunk & 7;                      \
            const int sblk = dblk ^ (row & 7);                                 \
            gload16(kbh + (size_t)row * HD + sblk * 8, &sKh[pb][0] + (size_t)cb * 8); \
            gload16(kbl + (size_t)row * HD + sblk * 8, &sKl[pb][0] + (size_t)cb * 8); \
            gload16(vbh + (size_t)row * SS + sblk * 8, &sVh[pb][0] + (size_t)cb * 8); \
            gload16(vbl + (size_t)row * SS + sblk * 8, &sVl[pb][0] + (size_t)cb * 8); \
        }                                                                      \
    }

    STAGE_TILE(0, 0)
    __syncthreads();

    for (int kt = 0; kt < nkt; ++kt) {
        const int pb = kt & 1;
        if (kt + 1 < nkt) STAGE_TILE(pb ^ 1, kt + 1)

        // ---- QK^T (swapped): C rows = keys, cols = q ----
        f32x4 sc[4][2];
        #pragma unroll
        for (int f = 0; f < 4; ++f)
            #pragma unroll
            for (int qf = 0; qf < 2; ++qf)
                sc[f][qf] = (f32x4){0.f, 0.f, 0.f, 0.f};

        #pragma unroll
        for (int ds_ = 0; ds_ < 2; ++ds_) {
            bf16x8 kh[4], kl[4];
            #pragma unroll
            for (int f = 0; f < 4; ++f) {
                const int addr = (16 * f + lr) * 64 + (((4 * ds_ + g) ^ (lr & 7)) * 8);
                kh[f] = *(const bf16x8*)&sKh[pb][addr];
                kl[f] = *(const bf16x8*)&sKl[pb][addr];
            }
            #pragma unroll
            for (int f = 0; f < 4; ++f)
                #pragma unroll
                for (int qf = 0; qf < 2; ++qf) {
                    sc[f][qf] = MFMA16(kh[f], qh[qf][ds_], sc[f][qf]);
                    sc[f][qf] = MFMA16(kl[f], qh[qf][ds_], sc[f][qf]);
                    sc[f][qf] = MFMA16(kh[f], ql[qf][ds_], sc[f][qf]);
                }
        }

        // ---- scale + causal mask + silu + pack bf16 hi/lo ----
        u32 pkh[4][2][2], pkl[4][2][2];
        #pragma unroll
        for (int f = 0; f < 4; ++f) {
            #pragma unroll
            for (int qf = 0; qf < 2; ++qf) {
                const int qrow = qt * 128 + w * 32 + qf * 16 + lr;
                float pv[4];
                #pragma unroll
                for (int r = 0; r < 4; ++r) {
                    const int key = kt * 64 + 16 * f + 4 * g + r;
                    const float x = sc[f][qf][r] * 0.125f;
                    pv[r] = (key <= qrow) ? silu_fast(x) : 0.0f;
                }
                #pragma unroll
                for (int t2 = 0; t2 < 2; ++t2) {
                    const ushort_t h0 = f2bf(pv[2 * t2]);
                    const ushort_t h1 = f2bf(pv[2 * t2 + 1]);
                    pkh[f][qf][t2] = (u32)h0 | ((u32)h1 << 16);
                    const float l0 = pv[2 * t2] - bf2f(h0);
                    const float l1 = pv[2 * t2 + 1] - bf2f(h1);
                    pkl[f][qf][t2] = (u32)f2bf(l0) | ((u32)f2bf(l1) << 16);
                }
            }
        }

        // ---- PV ----
        #pragma unroll
        for (int s2 = 0; s2 < 2; ++s2) {
            U8 ah[2], al[2];
            #pragma unroll
            for (int qf = 0; qf < 2; ++qf) {
                #pragma unroll
                for (int d = 0; d < 4; ++d) {
                    const int srcLane = lr + 16 * (2 * (g & 1) + (d >> 1));
                    const int t2 = d & 1;
                    int x0 = __shfl((int)pkh[2 * s2][qf][t2], srcLane, 64);
                    int x1 = __shfl((int)pkh[2 * s2 + 1][qf][t2], srcLane, 64);
                    ah[qf].d[d] = (g & 2) ? x1 : x0;
                    x0 = __shfl((int)pkl[2 * s2][qf][t2], srcLane, 64);
                    x1 = __shfl((int)pkl[2 * s2 + 1][qf][t2], srcLane, 64);
                    al[qf].d[d] = (g & 2) ? x1 : x0;
                }
            }
            #pragma unroll
            for (int df = 0; df < 4; ++df) {
                const int vaddr = (16 * df + lr) * 64 + (((4 * s2 + g) ^ (lr & 7)) * 8);
                const bf16x8 vh = *(const bf16x8*)&sVh[pb][vaddr];
                const bf16x8 vl = *(const bf16x8*)&sVl[pb][vaddr];
                #pragma unroll
                for (int qf = 0; qf < 2; ++qf) {
                    acc[qf][df] = MFMA16(ah[qf].v, vh, acc[qf][df]);
                    acc[qf][df] = MFMA16(al[qf].v, vh, acc[qf][df]);
                    acc[qf][df] = MFMA16(ah[qf].v, vl, acc[qf][df]);
                }
            }
        }

        __syncthreads();   // stage(kt+1) drained + all waves done with buf pb
    }

    #pragma unroll
    for (int qf = 0; qf < 2; ++qf) {
        #pragma unroll
        for (int df = 0; df < 4; ++df) {
            #pragma unroll
            for (int r = 0; r < 4; ++r) {
                const int row = qt * 128 + w * 32 + qf * 16 + 4 * g + r;
                attnOut[(size_t)(b * SS + row) * DD + h * HD + 16 * df + lr]
                    = acc[qf][df][r];
            }
        }
    }
#undef STAGE_TILE
}

// ---------------------------------------------------------------------------
// launch
// ---------------------------------------------------------------------------
extern "C" void kernel_launch(void* const* d_in, const int* in_sizes, int n_in,
                              void* d_out, int out_size, void* d_ws, size_t ws_size,
                              hipStream_t stream) {
    const float* x           = (const float*)d_in[0];
    const float* td          = (const float*)d_in[1];
    const float* uvqk_w      = (const float*)d_in[3];
    const float* uvqk_b      = (const float*)d_in[4];
    const float* gate_w      = (const float*)d_in[5];
    const float* out_w       = (const float*)d_in[6];
    const float* out_b       = (const float*)d_in[7];
    const float* in_norm_w   = (const float*)d_in[8];
    const float* last_norm_w = (const float*)d_in[9];
    const int*   pid         = (const int*)d_in[10];
    float* out = (float*)d_out;
    char*  ws  = (char*)d_ws;

    const size_t QKV = (size_t)BB * HH * SS * HD;      // 4.19M elems

    float* cosT = (float*)ws;                          ws += (size_t)BS * HD * 4;
    float* sinT = (float*)ws;                          ws += (size_t)BS * HD * 4;
    float* h    = (float*)ws;                          ws += (size_t)BS * DD * 4;
    float* uvqk = (float*)ws;                          ws += (size_t)BS * FOURD * 4;
    float* attn = (float*)ws;                          ws += (size_t)BS * DD * 4;
    ushort_t* h_hi  = (ushort_t*)ws;                   ws += (size_t)BS * DD * 2;
    ushort_t* h_lo  = (ushort_t*)ws;                   ws += (size_t)BS * DD * 2;
    ushort_t* g_hi  = (ushort_t*)ws;                   ws += (size_t)BS * DD * 2;
    ushort_t* g_lo  = (ushort_t*)ws;                   ws += (size_t)BS * DD * 2;
    ushort_t* uWt_hi = (ushort_t*)ws;                  ws += (size_t)FOURD * DD * 2;
    ushort_t* uWt_lo = (ushort_t*)ws;                  ws += (size_t)FOURD * DD * 2;
    ushort_t* oWt_hi = (ushort_t*)ws;                  ws += (size_t)DD * DD * 2;
    ushort_t* oWt_lo = (ushort_t*)ws;                  ws += (size_t)DD * DD * 2;
    ushort_t* q_hi  = (ushort_t*)ws;                   ws += QKV * 2;
    ushort_t* q_lo  = (ushort_t*)ws;                   ws += QKV * 2;
    ushort_t* k_hi  = (ushort_t*)ws;                   ws += QKV * 2;
    ushort_t* k_lo  = (ushort_t*)ws;                   ws += QKV * 2;
    ushort_t* vT_hi = (ushort_t*)ws;                   ws += QKV * 2;
    ushort_t* vT_lo = (ushort_t*)ws;                   ws += QKV * 2;
    (void)ws_size;

    rope_table_kernel<<<(BS * 32 + 255) / 256, 256, 0, stream>>>(td, pid, cosT, sinT);
    rmsnorm_kernel<<<BS, 256, 0, stream>>>(x, in_norm_w, nullptr, 0, h, h_hi, h_lo);

    for (int l = 0; l < LL; ++l) {
        wsplit_kernel<<<dim3(FOURD / 32, DD / 32), 256, 0, stream>>>(
            uvqk_w + (size_t)l * DD * FOURD, uWt_hi, uWt_lo, DD, FOURD);
        gemm3_kernel<<<dim3(FOURD / TBN, BS / TBM), 256, 0, stream>>>(
            h_hi, h_lo, uWt_hi, uWt_lo, uvqk_b + (size_t)l * FOURD,
            nullptr, uvqk, nullptr, nullptr, BS, FOURD, DD);
        postproc_kernel<<<BS, 256, 0, stream>>>(
            uvqk, cosT, sinT, q_hi, q_lo, k_hi, k_lo);
        vtrans_kernel<<<dim3(SS / 64, HH, BB), 256, 0, stream>>>(
            uvqk, vT_hi, vT_lo);
        attn_kernel<<<dim3(SS / 128, HH, BB), 256, 0, stream>>>(
            q_hi, q_lo, k_hi, k_lo, vT_hi, vT_lo, attn);
        rmsnorm_kernel<<<BS, 256, 0, stream>>>(
            attn, gate_w + (size_t)l * DD, uvqk, FOURD, attn, g_hi, g_lo);
        wsplit_kernel<<<dim3(DD / 32, DD / 32), 256, 0, stream>>>(
            out_w + (size_t)l * DD * DD, oWt_hi, oWt_lo, DD, DD);
        gemm3_kernel<<<dim3(DD / TBN, BS / TBM), 256, 0, stream>>>(
            g_hi, g_lo, oWt_hi, oWt_lo, out_b + (size_t)l * DD,
            h, h, h_hi, h_lo, BS, DD, DD);
    }

    rmsnorm_kernel<<<BS, 256, 0, stream>>>(h, last_norm_w, nullptr, 0, out, nullptr, nullptr);
}

// Round 6
// 1490.451 us; speedup vs baseline: 3.2746x; 1.1187x over previous
//
#include <hip/hip_runtime.h>
#include <hip/hip_bf16.h>
#include <math.h>

// Problem constants: B=2, S=2048, D=1024, H=16, HD=64, L=4
#define BB 2
#define SS 2048
#define DD 1024
#define HH 16
#define HD 64
#define LL 4
#define BS (BB * SS)          // 4096 tokens
#define FOURD (4 * DD)        // 4096

typedef unsigned int u32;
typedef unsigned short ushort_t;
typedef __attribute__((ext_vector_type(8))) short bf16x8;
typedef __attribute__((ext_vector_type(4))) float f32x4;

__device__ __forceinline__ float silu_f(float x) {
    return x / (1.0f + expf(-x));
}
// hot-loop silu: v_exp + v_rcp (rel err ~1e-7, invisible vs 1.6e-2 abs floor)
__device__ __forceinline__ float silu_fast(float x) {
    return x * __builtin_amdgcn_rcpf(1.0f + __expf(-x));
}

// bf16 round-to-nearest-even split helpers
__device__ __forceinline__ ushort_t f2bf(float x) {
    u32 u = __float_as_uint(x);
    u32 r = (u + 0x7fffu + ((u >> 16) & 1u)) >> 16;
    return (ushort_t)r;
}
__device__ __forceinline__ float bf2f(ushort_t h) {
    return __uint_as_float((u32)h << 16);
}

// async global->LDS, 16B per lane; lds dest = wave-uniform base + lane*16
typedef __attribute__((address_space(3))) u32 lds_u32;
typedef const __attribute__((address_space(1))) u32 glb_u32;
__device__ __forceinline__ void gload16(const void* g, const void* lds) {
    __builtin_amdgcn_global_load_lds((glb_u32*)(uintptr_t)g,
                                     (lds_u32*)(uintptr_t)lds, 16, 0, 0);
}

#define MFMA16(a, b, c) __builtin_amdgcn_mfma_f32_16x16x32_bf16((a), (b), (c), 0, 0, 0)

union U8 { u32 d[4]; bf16x8 v; };

// ---------------------------------------------------------------------------
// RoPE tables: cos/sin [BS][HD]; pos = position_id + 0.1*log(dt+1)
// ---------------------------------------------------------------------------
__global__ __launch_bounds__(256) void rope_table_kernel(
    const float* __restrict__ td, const int* __restrict__ pid,
    float* __restrict__ cosT, float* __restrict__ sinT)
{
    int idx = blockIdx.x * blockDim.x + threadIdx.x;   // over BS*32
    if (idx >= BS * 32) return;
    int i = idx & 31, bs = idx >> 5;
    float pos = (float)pid[bs] + 0.1f * logf(td[bs] + 1.0f);
    float inv = powf(10000.0f, -(float)(2 * i) / 64.0f);
    float f = pos * inv;
    float c = cosf(f), s = sinf(f);
    cosT[bs * HD + i] = c;  cosT[bs * HD + i + 32] = c;
    sinT[bs * HD + i] = s;  sinT[bs * HD + i + 32] = s;
}

// ---------------------------------------------------------------------------
// RMSNorm over D=1024; optional elementwise multiplier; optional bf16 hi/lo
// ---------------------------------------------------------------------------
__global__ __launch_bounds__(256) void rmsnorm_kernel(
    const float* __restrict__ in, const float* __restrict__ w,
    const float* __restrict__ mul, int mulStride,
    float* __restrict__ out,
    ushort_t* __restrict__ hi, ushort_t* __restrict__ lo)
{
    __shared__ float red[4];
    int row = blockIdx.x, t = threadIdx.x;
    const float4 v = *(const float4*)&in[(size_t)row * DD + t * 4];
    float ss = v.x * v.x + v.y * v.y + v.z * v.z + v.w * v.w;
    #pragma unroll
    for (int o = 32; o > 0; o >>= 1) ss += __shfl_down(ss, o);
    if ((t & 63) == 0) red[t >> 6] = ss;
    __syncthreads();
    float tot = red[0] + red[1] + red[2] + red[3];
    float r = rsqrtf(tot * (1.0f / (float)DD) + 1e-6f);
    const float4 wv = *(const float4*)&w[t * 4];
    float4 o4;
    o4.x = v.x * r * wv.x;  o4.y = v.y * r * wv.y;
    o4.z = v.z * r * wv.z;  o4.w = v.w * r * wv.w;
    if (mul) {
        const float4 m = *(const float4*)&mul[(size_t)row * mulStride + t * 4];
        o4.x *= m.x; o4.y *= m.y; o4.z *= m.z; o4.w *= m.w;
    }
    const size_t o = (size_t)row * DD + t * 4;
    *(float4*)&out[o] = o4;
    if (hi) {
        ushort4 h4, l4;
        float e;
        h4.x = f2bf(o4.x); e = o4.x - bf2f(h4.x); l4.x = f2bf(e);
        h4.y = f2bf(o4.y); e = o4.y - bf2f(h4.y); l4.y = f2bf(e);
        h4.z = f2bf(o4.z); e = o4.z - bf2f(h4.z); l4.z = f2bf(e);
        h4.w = f2bf(o4.w); e = o4.w - bf2f(h4.w); l4.w = f2bf(e);
        *(ushort4*)&hi[o] = h4;
        *(ushort4*)&lo[o] = l4;
    }
}

// ---------------------------------------------------------------------------
// Weight transpose + bf16 split: W [K][N] fp32 -> Wt_hi/Wt_lo [N][K] bf16
// ---------------------------------------------------------------------------
__global__ __launch_bounds__(256) void wsplit_kernel(
    const float* __restrict__ W, ushort_t* __restrict__ hi,
    ushort_t* __restrict__ lo, int K, int N)
{
    __shared__ float T[32][33];
    const int n0 = blockIdx.x * 32, k0 = blockIdx.y * 32;
    const int t = threadIdx.x;
    {
        const int r = t >> 3, cg = (t & 7) * 4;
        const float4 v = *(const float4*)&W[(size_t)(k0 + r) * N + n0 + cg];
        T[r][cg] = v.x; T[r][cg + 1] = v.y; T[r][cg + 2] = v.z; T[r][cg + 3] = v.w;
    }
    __syncthreads();
    {
        const int n = t >> 3, kg = (t & 7) * 4;
        ushort4 h4, l4;
        float x, e;
        x = T[kg + 0][n]; h4.x = f2bf(x); e = x - bf2f(h4.x); l4.x = f2bf(e);
        x = T[kg + 1][n]; h4.y = f2bf(x); e = x - bf2f(h4.y); l4.y = f2bf(e);
        x = T[kg + 2][n]; h4.z = f2bf(x); e = x - bf2f(h4.z); l4.z = f2bf(e);
        x = T[kg + 3][n]; h4.w = f2bf(x); e = x - bf2f(h4.w); l4.w = f2bf(e);
        const size_t o = (size_t)(n0 + n) * K + k0 + kg;
        *(ushort4*)&hi[o] = h4;
        *(ushort4*)&lo[o] = l4;
    }
}

// ---------------------------------------------------------------------------
// bf16x3 MFMA GEMM (unchanged)
// ---------------------------------------------------------------------------
#define TBM 128
#define TBN 128
#define TBK 32
__global__ __launch_bounds__(256) void gemm3_kernel(
    const ushort_t* __restrict__ Ah, const ushort_t* __restrict__ Al,
    const ushort_t* __restrict__ Bh, const ushort_t* __restrict__ Bl,
    const float* __restrict__ bias, const float* __restrict__ res,
    float* __restrict__ C, ushort_t* __restrict__ Chi, ushort_t* __restrict__ Clo,
    int M, int N, int K)
{
    __shared__ ushort_t sAh[TBM][TBK];
    __shared__ ushort_t sAl[TBM][TBK];
    __shared__ ushort_t sBh[TBN][TBK];
    __shared__ ushort_t sBl[TBN][TBK];

    const int tid = threadIdx.x;
    const int w = tid >> 6, l = tid & 63;
    const int wr = w >> 1, wc = w & 1;
    const int m0 = blockIdx.y * TBM, n0 = blockIdx.x * TBN;
    const int lr = l & 15, lk = (l >> 4) * 8;

    f32x4 acc[4][4];
    #pragma unroll
    for (int m = 0; m < 4; ++m)
        #pragma unroll
        for (int n = 0; n < 4; ++n)
            acc[m][n] = (f32x4){0.f, 0.f, 0.f, 0.f};

    for (int k0 = 0; k0 < K; k0 += TBK) {
        if (k0) __syncthreads();
        #pragma unroll
        for (int i = 0; i < 2; ++i) {
            const int cb = i * 256 + w * 64;
            const int chunk = cb + l;
            const int row = chunk >> 2;
            const int kc = (chunk & 3) * 8;
            const size_t ga = (size_t)(m0 + row) * K + k0 + kc;
            const size_t gb = (size_t)(n0 + row) * K + k0 + kc;
            gload16(Ah + ga, &sAh[0][0] + (size_t)cb * 8);
            gload16(Al + ga, &sAl[0][0] + (size_t)cb * 8);
            gload16(Bh + gb, &sBh[0][0] + (size_t)cb * 8);
            gload16(Bl + gb, &sBl[0][0] + (size_t)cb * 8);
        }
        __syncthreads();

        bf16x8 ah[4], al[4], bh[4], bl[4];
        #pragma unroll
        for (int m = 0; m < 4; ++m) {
            ah[m] = *(const bf16x8*)&sAh[wr * 64 + m * 16 + lr][lk];
            al[m] = *(const bf16x8*)&sAl[wr * 64 + m * 16 + lr][lk];
        }
        #pragma unroll
        for (int n = 0; n < 4; ++n) {
            bh[n] = *(const bf16x8*)&sBh[wc * 64 + n * 16 + lr][lk];
            bl[n] = *(const bf16x8*)&sBl[wc * 64 + n * 16 + lr][lk];
        }
        #pragma unroll
        for (int m = 0; m < 4; ++m) {
            #pragma unroll
            for (int n = 0; n < 4; ++n) {
                acc[m][n] = MFMA16(ah[m], bh[n], acc[m][n]);
                acc[m][n] = MFMA16(al[m], bh[n], acc[m][n]);
                acc[m][n] = MFMA16(ah[m], bl[n], acc[m][n]);
            }
        }
    }

    #pragma unroll
    for (int m = 0; m < 4; ++m) {
        #pragma unroll
        for (int n = 0; n < 4; ++n) {
            const int col = n0 + wc * 64 + n * 16 + lr;
            #pragma unroll
            for (int r = 0; r < 4; ++r) {
                const int row = m0 + wr * 64 + m * 16 + (l >> 4) * 4 + r;
                const size_t o = (size_t)row * N + col;
                float v = acc[m][n][r] + bias[col];
                if (res) v += res[o];
                C[o] = v;
                if (Chi) {
                    ushort_t hv = f2bf(v);
                    Chi[o] = hv;
                    Clo[o] = f2bf(v - bf2f(hv));
                }
            }
        }
    }
}

// ---------------------------------------------------------------------------
// Post-process: u <- silu(u) in place; q,k <- RoPE -> head-major bf16 hi/lo
// [b][h][s][64].  (V handled by vtrans_kernel.)  Paired u32 stores.
// ---------------------------------------------------------------------------
__global__ __launch_bounds__(256) void postproc_kernel(
    float* __restrict__ uvqk,
    const float* __restrict__ cosT, const float* __restrict__ sinT,
    ushort_t* __restrict__ q_hi, ushort_t* __restrict__ q_lo,
    ushort_t* __restrict__ k_hi, ushort_t* __restrict__ k_lo)
{
    const int bs = blockIdx.x, t = threadIdx.x;
    const int b = bs >> 11, s = bs & (SS - 1);
    float* base = uvqk + (size_t)bs * FOURD;

    float4 u = *(float4*)&base[t * 4];
    u.x = silu_f(u.x); u.y = silu_f(u.y); u.z = silu_f(u.z); u.w = silu_f(u.w);
    *(float4*)&base[t * 4] = u;

    const int hh = t >> 4, p = (t & 15) * 2;
    const float c0 = cosT[bs * HD + p], c1 = cosT[bs * HD + p + 1];
    const float s0 = sinT[bs * HD + p], s1 = sinT[bs * HD + p + 1];
    const size_t hrow = ((size_t)(b * HH + hh) * SS + s) * HD;
    #pragma unroll
    for (int sect = 2; sect <= 3; ++sect) {
        const float* qp = base + sect * DD + hh * HD;
        const float a0 = qp[p], a1 = qp[p + 1];
        const float b0 = qp[p + 32], b1 = qp[p + 33];
        float o0 = a0 * c0 - b0 * s0;
        float o1 = a1 * c1 - b1 * s1;
        float o2 = b0 * c0 + a0 * s0;
        float o3 = b1 * c1 + a1 * s1;
        ushort_t* dh = (sect == 2) ? q_hi : k_hi;
        ushort_t* dl = (sect == 2) ? q_lo : k_lo;
        const ushort_t h0 = f2bf(o0), h1 = f2bf(o1);
        const ushort_t h2 = f2bf(o2), h3 = f2bf(o3);
        *(u32*)&dh[hrow + p]      = (u32)h0 | ((u32)h1 << 16);
        *(u32*)&dh[hrow + p + 32] = (u32)h2 | ((u32)h3 << 16);
        *(u32*)&dl[hrow + p]      = (u32)f2bf(o0 - bf2f(h0))
                                  | ((u32)f2bf(o1 - bf2f(h1)) << 16);
        *(u32*)&dl[hrow + p + 32] = (u32)f2bf(o2 - bf2f(h2))
                                  | ((u32)f2bf(o3 - bf2f(h3)) << 16);
    }
}

// ---------------------------------------------------------------------------
// V transpose + split: v slice of uvqk -> vT_hi/lo [b][h][d][s], coalesced.
// ---------------------------------------------------------------------------
__global__ __launch_bounds__(256) void vtrans_kernel(
    const float* __restrict__ uvqk,
    ushort_t* __restrict__ vT_hi, ushort_t* __restrict__ vT_lo)
{
    __shared__ float T[64][65];
    const int sb = blockIdx.x, h = blockIdx.y, b = blockIdx.z;
    const int t = threadIdx.x;
    const int s0 = sb * 64;
    #pragma unroll
    for (int it = 0; it < 4; ++it) {
        const int idx = it * 256 + t;          // 0..1023
        const int row = idx >> 4, c4 = (idx & 15) * 4;
        const float4 v = *(const float4*)&uvqk[
            (size_t)(b * SS + s0 + row) * FOURD + DD + h * HD + c4];
        T[row][c4] = v.x; T[row][c4 + 1] = v.y;
        T[row][c4 + 2] = v.z; T[row][c4 + 3] = v.w;
    }
    __syncthreads();
    const int d = t >> 2, sc = (t & 3) * 16;
    u32 hw[8], lw[8];
    #pragma unroll
    for (int j = 0; j < 8; ++j) {
        const float x0 = T[sc + 2 * j][d];
        const float x1 = T[sc + 2 * j + 1][d];
        const ushort_t h0 = f2bf(x0), h1 = f2bf(x1);
        hw[j] = (u32)h0 | ((u32)h1 << 16);
        lw[j] = (u32)f2bf(x0 - bf2f(h0)) | ((u32)f2bf(x1 - bf2f(h1)) << 16);
    }
    const size_t o = ((size_t)(b * HH + h) * HD + d) * SS + s0 + sc;
    *(uint4*)&vT_hi[o] = make_uint4(hw[0], hw[1], hw[2], hw[3]);
    *(uint4*)&vT_hi[o + 8] = make_uint4(hw[4], hw[5], hw[6], hw[7]);
    *(uint4*)&vT_lo[o] = make_uint4(lw[0], lw[1], lw[2], lw[3]);
    *(uint4*)&vT_lo[o + 8] = make_uint4(lw[4], lw[5], lw[6], lw[7]);
}

// ---------------------------------------------------------------------------
// MFMA causal SiLU attention. Block: 128 q-rows x (b,h); 4 waves x 32 rows.
// Changes this round:
//  - qt anti-correlated with batch (b=0: 15-x, b=1: x) so each CU's two
//    resident blocks sum to a constant 34 tile-units (load balance).
//  - wave-level skip of fully-masked k-tiles.
//  - truncating bf16 split in P-pack (lo compensates hi; rounding mode of
//    hi is irrelevant).
//  - silu via v_rcp instead of v_div.
// ---------------------------------------------------------------------------
__global__ __launch_bounds__(256) void attn_kernel(
    const ushort_t* __restrict__ q_hi, const ushort_t* __restrict__ q_lo,
    const ushort_t* __restrict__ k_hi, const ushort_t* __restrict__ k_lo,
    const ushort_t* __restrict__ vT_hi, const ushort_t* __restrict__ vT_lo,
    float* __restrict__ attnOut)
{
    __shared__ ushort_t sKh[2][64 * 64];
    __shared__ ushort_t sKl[2][64 * 64];
    __shared__ ushort_t sVh[2][64 * 64];
    __shared__ ushort_t sVl[2][64 * 64];

    const int h = blockIdx.y, b = blockIdx.z;
    // load balance: CU gets linear ids c (b=0) and c+256 (b=1) with the same
    // blockIdx.x -> make their qt sum constant.
    const int qt = b ? blockIdx.x : (SS / 128 - 1) - blockIdx.x;
    const int tid = threadIdx.x;
    const int w = tid >> 6, l = tid & 63;
    const int lr = l & 15, g = l >> 4;

    const size_t headQ = ((size_t)(b * HH + h) * SS) * HD;
    const size_t headV = ((size_t)(b * HH + h) * HD) * SS;

    bf16x8 qh[2][2], ql[2][2];
    {
        const int qrow0 = qt * 128 + w * 32;
        #pragma unroll
        for (int qf = 0; qf < 2; ++qf)
            #pragma unroll
            for (int ds_ = 0; ds_ < 2; ++ds_) {
                const size_t off = headQ + (size_t)(qrow0 + qf * 16 + lr) * HD
                                   + ds_ * 32 + g * 8;
                qh[qf][ds_] = *(const bf16x8*)&q_hi[off];
                ql[qf][ds_] = *(const bf16x8*)&q_lo[off];
            }
    }

    f32x4 acc[2][4];
    #pragma unroll
    for (int qf = 0; qf < 2; ++qf)
        #pragma unroll
        for (int df = 0; df < 4; ++df)
            acc[qf][df] = (f32x4){0.f, 0.f, 0.f, 0.f};

    const int nkt = 2 * qt + 2;

#define STAGE_TILE(pb, kt_)                                                    \
    {                                                                          \
        const ushort_t* kbh = k_hi + headQ + (size_t)(kt_) * 64 * HD;          \
        const ushort_t* kbl = k_lo + headQ + (size_t)(kt_) * 64 * HD;          \
        const ushort_t* vbh = vT_hi + headV + (kt_) * 64;                      \
        const ushort_t* vbl = vT_lo + headV + (kt_) * 64;                      \
        _Pragma("unroll")                                                      \
        for (int rep = 0; rep < 2; ++rep) {                                    \
            const int cb = rep * 256 + w * 64;                                 \
            const int chunk = cb + l;                                          \
            const int row = chunk >> 3, dblk = chunk & 7;                      \
            const int sblk = dblk ^ (row & 7);                                 \
            gload16(kbh + (size_t)row * HD + sblk * 8, &sKh[pb][0] + (size_t)cb * 8); \
            gload16(kbl + (size_t)row * HD + sblk * 8, &sKl[pb][0] + (size_t)cb * 8); \
            gload16(vbh + (size_t)row * SS + sblk * 8, &sVh[pb][0] + (size_t)cb * 8); \
            gload16(vbl + (size_t)row * SS + sblk * 8, &sVl[pb][0] + (size_t)cb * 8); \
        }                                                                      \
    }

    STAGE_TILE(0, 0)
    __syncthreads();

    for (int kt = 0; kt < nkt; ++kt) {
        const int pb = kt & 1;
        if (kt + 1 < nkt) STAGE_TILE(pb ^ 1, kt + 1)

        // wave-level causal skip: tile fully masked for this wave's rows
        if (kt * 64 <= qt * 128 + w * 32 + 31) {

        // ---- QK^T (swapped): C rows = keys, cols = q ----
        f32x4 sc[4][2];
        #pragma unroll
        for (int f = 0; f < 4; ++f)
            #pragma unroll
            for (int qf = 0; qf < 2; ++qf)
                sc[f][qf] = (f32x4){0.f, 0.f, 0.f, 0.f};

        #pragma unroll
        for (int ds_ = 0; ds_ < 2; ++ds_) {
            bf16x8 kh[4], kl[4];
            #pragma unroll
            for (int f = 0; f < 4; ++f) {
                const int addr = (16 * f + lr) * 64 + (((4 * ds_ + g) ^ (lr & 7)) * 8);
                kh[f] = *(const bf16x8*)&sKh[pb][addr];
                kl[f] = *(const bf16x8*)&sKl[pb][addr];
            }
            #pragma unroll
            for (int f = 0; f < 4; ++f)
                #pragma unroll
                for (int qf = 0; qf < 2; ++qf) {
                    sc[f][qf] = MFMA16(kh[f], qh[qf][ds_], sc[f][qf]);
                    sc[f][qf] = MFMA16(kl[f], qh[qf][ds_], sc[f][qf]);
                    sc[f][qf] = MFMA16(kh[f], ql[qf][ds_], sc[f][qf]);
                }
        }

        // ---- scale + causal mask + silu + truncating pack bf16 hi/lo ----
        u32 pkh[4][2][2], pkl[4][2][2];
        #pragma unroll
        for (int f = 0; f < 4; ++f) {
            #pragma unroll
            for (int qf = 0; qf < 2; ++qf) {
                const int qrow = qt * 128 + w * 32 + qf * 16 + lr;
                float pv[4];
                #pragma unroll
                for (int r = 0; r < 4; ++r) {
                    const int key = kt * 64 + 16 * f + 4 * g + r;
                    const float x = sc[f][qf][r] * 0.125f;
                    pv[r] = (key <= qrow) ? silu_fast(x) : 0.0f;
                }
                #pragma unroll
                for (int t2 = 0; t2 < 2; ++t2) {
                    const u32 u0 = __float_as_uint(pv[2 * t2]);
                    const u32 u1 = __float_as_uint(pv[2 * t2 + 1]);
                    const u32 h0 = u0 >> 16, h1 = u1 >> 16;
                    pkh[f][qf][t2] = h0 | (h1 << 16);
                    const float l0 = pv[2 * t2]     - __uint_as_float(h0 << 16);
                    const float l1 = pv[2 * t2 + 1] - __uint_as_float(h1 << 16);
                    pkl[f][qf][t2] = (__float_as_uint(l0) >> 16)
                                   | ((__float_as_uint(l1) >> 16) << 16);
                }
            }
        }

        // ---- PV ----
        #pragma unroll
        for (int s2 = 0; s2 < 2; ++s2) {
            U8 ah[2], al[2];
            #pragma unroll
            for (int qf = 0; qf < 2; ++qf) {
                #pragma unroll
                for (int d = 0; d < 4; ++d) {
                    const int srcLane = lr + 16 * (2 * (g & 1) + (d >> 1));
                    const int t2 = d & 1;
                    int x0 = __shfl((int)pkh[2 * s2][qf][t2], srcLane, 64);
                    int x1 = __shfl((int)pkh[2 * s2 + 1][qf][t2], srcLane, 64);
                    ah[qf].d[d] = (g & 2) ? x1 : x0;
                    x0 = __shfl((int)pkl[2 * s2][qf][t2], srcLane, 64);
                    x1 = __shfl((int)pkl[2 * s2 + 1][qf][t2], srcLane, 64);
                    al[qf].d[d] = (g & 2) ? x1 : x0;
                }
            }
            #pragma unroll
            for (int df = 0; df < 4; ++df) {
                const int vaddr = (16 * df + lr) * 64 + (((4 * s2 + g) ^ (lr & 7)) * 8);
                const bf16x8 vh = *(const bf16x8*)&sVh[pb][vaddr];
                const bf16x8 vl = *(const bf16x8*)&sVl[pb][vaddr];
                #pragma unroll
                for (int qf = 0; qf < 2; ++qf) {
                    acc[qf][df] = MFMA16(ah[qf].v, vh, acc[qf][df]);
                    acc[qf][df] = MFMA16(al[qf].v, vh, acc[qf][df]);
                    acc[qf][df] = MFMA16(ah[qf].v, vl, acc[qf][df]);
                }
            }
        }

        } // end causal-skip

        __syncthreads();   // stage(kt+1) drained + all waves done with buf pb
    }

    #pragma unroll
    for (int qf = 0; qf < 2; ++qf) {
        #pragma unroll
        for (int df = 0; df < 4; ++df) {
            #pragma unroll
            for (int r = 0; r < 4; ++r) {
                const int row = qt * 128 + w * 32 + qf * 16 + 4 * g + r;
                attnOut[(size_t)(b * SS + row) * DD + h * HD + 16 * df + lr]
                    = acc[qf][df][r];
            }
        }
    }
#undef STAGE_TILE
}

// ---------------------------------------------------------------------------
// launch
// ---------------------------------------------------------------------------
extern "C" void kernel_launch(void* const* d_in, const int* in_sizes, int n_in,
                              void* d_out, int out_size, void* d_ws, size_t ws_size,
                              hipStream_t stream) {
    const float* x           = (const float*)d_in[0];
    const float* td          = (const float*)d_in[1];
    const float* uvqk_w      = (const float*)d_in[3];
    const float* uvqk_b      = (const float*)d_in[4];
    const float* gate_w      = (const float*)d_in[5];
    const float* out_w       = (const float*)d_in[6];
    const float* out_b       = (const float*)d_in[7];
    const float* in_norm_w   = (const float*)d_in[8];
    const float* last_norm_w = (const float*)d_in[9];
    const int*   pid         = (const int*)d_in[10];
    float* out = (float*)d_out;
    char*  ws  = (char*)d_ws;

    const size_t QKV = (size_t)BB * HH * SS * HD;      // 4.19M elems

    float* cosT = (float*)ws;                          ws += (size_t)BS * HD * 4;
    float* sinT = (float*)ws;                          ws += (size_t)BS * HD * 4;
    float* h    = (float*)ws;                          ws += (size_t)BS * DD * 4;
    float* uvqk = (float*)ws;                          ws += (size_t)BS * FOURD * 4;
    float* attn = (float*)ws;                          ws += (size_t)BS * DD * 4;
    ushort_t* h_hi  = (ushort_t*)ws;                   ws += (size_t)BS * DD * 2;
    ushort_t* h_lo  = (ushort_t*)ws;                   ws += (size_t)BS * DD * 2;
    ushort_t* g_hi  = (ushort_t*)ws;                   ws += (size_t)BS * DD * 2;
    ushort_t* g_lo  = (ushort_t*)ws;                   ws += (size_t)BS * DD * 2;
    ushort_t* uWt_hi = (ushort_t*)ws;                  ws += (size_t)FOURD * DD * 2;
    ushort_t* uWt_lo = (ushort_t*)ws;                  ws += (size_t)FOURD * DD * 2;
    ushort_t* oWt_hi = (ushort_t*)ws;                  ws += (size_t)DD * DD * 2;
    ushort_t* oWt_lo = (ushort_t*)ws;                  ws += (size_t)DD * DD * 2;
    ushort_t* q_hi  = (ushort_t*)ws;                   ws += QKV * 2;
    ushort_t* q_lo  = (ushort_t*)ws;                   ws += QKV * 2;
    ushort_t* k_hi  = (ushort_t*)ws;                   ws += QKV * 2;
    ushort_t* k_lo  = (ushort_t*)ws;                   ws += QKV * 2;
    ushort_t* vT_hi = (ushort_t*)ws;                   ws += QKV * 2;
    ushort_t* vT_lo = (ushort_t*)ws;                   ws += QKV * 2;
    (void)ws_size;

    rope_table_kernel<<<(BS * 32 + 255) / 256, 256, 0, stream>>>(td, pid, cosT, sinT);
    rmsnorm_kernel<<<BS, 256, 0, stream>>>(x, in_norm_w, nullptr, 0, h, h_hi, h_lo);

    for (int l = 0; l < LL; ++l) {
        wsplit_kernel<<<dim3(FOURD / 32, DD / 32), 256, 0, stream>>>(
            uvqk_w + (size_t)l * DD * FOURD, uWt_hi, uWt_lo, DD, FOURD);
        gemm3_kernel<<<dim3(FOURD / TBN, BS / TBM), 256, 0, stream>>>(
            h_hi, h_lo, uWt_hi, uWt_lo, uvqk_b + (size_t)l * FOURD,
            nullptr, uvqk, nullptr, nullptr, BS, FOURD, DD);
        postproc_kernel<<<BS, 256, 0, stream>>>(
            uvqk, cosT, sinT, q_hi, q_lo, k_hi, k_lo);
        vtrans_kernel<<<dim3(SS / 64, HH, BB), 256, 0, stream>>>(
            uvqk, vT_hi, vT_lo);
        attn_kernel<<<dim3(SS / 128, HH, BB), 256, 0, stream>>>(
            q_hi, q_lo, k_hi, k_lo, vT_hi, vT_lo, attn);
        rmsnorm_kernel<<<BS, 256, 0, stream>>>(
            attn, gate_w + (size_t)l * DD, uvqk, FOURD, attn, g_hi, g_lo);
        wsplit_kernel<<<dim3(DD / 32, DD / 32), 256, 0, stream>>>(
            out_w + (size_t)l * DD * DD, oWt_hi, oWt_lo, DD, DD);
        gemm3_kernel<<<dim3(DD / TBN, BS / TBM), 256, 0, stream>>>(
            g_hi, g_lo, oWt_hi, oWt_lo, out_b + (size_t)l * DD,
            h, h, h_hi, h_lo, BS, DD, DD);
    }

    rmsnorm_kernel<<<BS, 256, 0, stream>>>(h, last_norm_w, nullptr, 0, out, nullptr, nullptr);
}

// Round 8
// 1469.890 us; speedup vs baseline: 3.3204x; 1.0140x over previous
//
#include <hip/hip_runtime.h>
#include <hip/hip_bf16.h>
#include <math.h>

// Problem constants: B=2, S=2048, D=1024, H=16, HD=64, L=4
#define BB 2
#define SS 2048
#define DD 1024
#define HH 16
#define HD 64
#define LL 4
#define BS (BB * SS)          // 4096 tokens
#define FOURD (4 * DD)        // 4096

typedef unsigned int u32;
typedef unsigned short ushort_t;
typedef __attribute__((ext_vector_type(8))) short bf16x8;
typedef __attribute__((ext_vector_type(4))) float f32x4;

__device__ __forceinline__ float silu_f(float x) {
    return x / (1.0f + expf(-x));
}
// hot-loop silu: v_exp + v_rcp (rel err ~1e-7)
__device__ __forceinline__ float silu_fast(float x) {
    return x * __builtin_amdgcn_rcpf(1.0f + __expf(-x));
}

// bf16 round-to-nearest-even split helpers
__device__ __forceinline__ ushort_t f2bf(float x) {
    u32 u = __float_as_uint(x);
    u32 r = (u + 0x7fffu + ((u >> 16) & 1u)) >> 16;
    return (ushort_t)r;
}
__device__ __forceinline__ float bf2f(ushort_t h) {
    return __uint_as_float((u32)h << 16);
}

// async global->LDS, 16B per lane; lds dest = wave-uniform base + lane*16
typedef __attribute__((address_space(3))) u32 lds_u32;
typedef const __attribute__((address_space(1))) u32 glb_u32;
__device__ __forceinline__ void gload16(const void* g, const void* lds) {
    __builtin_amdgcn_global_load_lds((glb_u32*)(uintptr_t)g,
                                     (lds_u32*)(uintptr_t)lds, 16, 0, 0);
}

#define MFMA16(a, b, c) __builtin_amdgcn_mfma_f32_16x16x32_bf16((a), (b), (c), 0, 0, 0)

union U8 { u32 d[4]; bf16x8 v; };

// ---------------------------------------------------------------------------
// RoPE tables: cos/sin [BS][HD]; pos = position_id + 0.1*log(dt+1)
// ---------------------------------------------------------------------------
__global__ __launch_bounds__(256) void rope_table_kernel(
    const float* __restrict__ td, const int* __restrict__ pid,
    float* __restrict__ cosT, float* __restrict__ sinT)
{
    int idx = blockIdx.x * blockDim.x + threadIdx.x;   // over BS*32
    if (idx >= BS * 32) return;
    int i = idx & 31, bs = idx >> 5;
    float pos = (float)pid[bs] + 0.1f * logf(td[bs] + 1.0f);
    float inv = powf(10000.0f, -(float)(2 * i) / 64.0f);
    float f = pos * inv;
    float c = cosf(f), s = sinf(f);
    cosT[bs * HD + i] = c;  cosT[bs * HD + i + 32] = c;
    sinT[bs * HD + i] = s;  sinT[bs * HD + i + 32] = s;
}

// ---------------------------------------------------------------------------
// RMSNorm over D=1024; optional elementwise multiplier (optionally silu'd);
// optional bf16 hi/lo split outputs.
// ---------------------------------------------------------------------------
__global__ __launch_bounds__(256) void rmsnorm_kernel(
    const float* __restrict__ in, const float* __restrict__ w,
    const float* __restrict__ mul, int mulStride, int siluMul,
    float* __restrict__ out,
    ushort_t* __restrict__ hi, ushort_t* __restrict__ lo)
{
    __shared__ float red[4];
    int row = blockIdx.x, t = threadIdx.x;
    const float4 v = *(const float4*)&in[(size_t)row * DD + t * 4];
    float ss = v.x * v.x + v.y * v.y + v.z * v.z + v.w * v.w;
    #pragma unroll
    for (int o = 32; o > 0; o >>= 1) ss += __shfl_down(ss, o);
    if ((t & 63) == 0) red[t >> 6] = ss;
    __syncthreads();
    float tot = red[0] + red[1] + red[2] + red[3];
    float r = rsqrtf(tot * (1.0f / (float)DD) + 1e-6f);
    const float4 wv = *(const float4*)&w[t * 4];
    float4 o4;
    o4.x = v.x * r * wv.x;  o4.y = v.y * r * wv.y;
    o4.z = v.z * r * wv.z;  o4.w = v.w * r * wv.w;
    if (mul) {
        float4 m = *(const float4*)&mul[(size_t)row * mulStride + t * 4];
        if (siluMul) {
            m.x = silu_f(m.x); m.y = silu_f(m.y);
            m.z = silu_f(m.z); m.w = silu_f(m.w);
        }
        o4.x *= m.x; o4.y *= m.y; o4.z *= m.z; o4.w *= m.w;
    }
    const size_t o = (size_t)row * DD + t * 4;
    *(float4*)&out[o] = o4;
    if (hi) {
        ushort4 h4, l4;
        float e;
        h4.x = f2bf(o4.x); e = o4.x - bf2f(h4.x); l4.x = f2bf(e);
        h4.y = f2bf(o4.y); e = o4.y - bf2f(h4.y); l4.y = f2bf(e);
        h4.z = f2bf(o4.z); e = o4.z - bf2f(h4.z); l4.z = f2bf(e);
        h4.w = f2bf(o4.w); e = o4.w - bf2f(h4.w); l4.w = f2bf(e);
        *(ushort4*)&hi[o] = h4;
        *(ushort4*)&lo[o] = l4;
    }
}

// ---------------------------------------------------------------------------
// Weight transpose + bf16 split: W [K][N] fp32 -> Wt_hi/Wt_lo [N][K] bf16
// ---------------------------------------------------------------------------
__global__ __launch_bounds__(256) void wsplit_kernel(
    const float* __restrict__ W, ushort_t* __restrict__ hi,
    ushort_t* __restrict__ lo, int K, int N)
{
    __shared__ float T[32][33];
    const int n0 = blockIdx.x * 32, k0 = blockIdx.y * 32;
    const int t = threadIdx.x;
    {
        const int r = t >> 3, cg = (t & 7) * 4;
        const float4 v = *(const float4*)&W[(size_t)(k0 + r) * N + n0 + cg];
        T[r][cg] = v.x; T[r][cg + 1] = v.y; T[r][cg + 2] = v.z; T[r][cg + 3] = v.w;
    }
    __syncthreads();
    {
        const int n = t >> 3, kg = (t & 7) * 4;
        ushort4 h4, l4;
        float x, e;
        x = T[kg + 0][n]; h4.x = f2bf(x); e = x - bf2f(h4.x); l4.x = f2bf(e);
        x = T[kg + 1][n]; h4.y = f2bf(x); e = x - bf2f(h4.y); l4.y = f2bf(e);
        x = T[kg + 2][n]; h4.z = f2bf(x); e = x - bf2f(h4.z); l4.z = f2bf(e);
        x = T[kg + 3][n]; h4.w = f2bf(x); e = x - bf2f(h4.w); l4.w = f2bf(e);
        const size_t o = (size_t)(n0 + n) * K + k0 + kg;
        *(ushort4*)&hi[o] = h4;
        *(ushort4*)&lo[o] = l4;
    }
}

// ---------------------------------------------------------------------------
// bf16x3 MFMA GEMM (unchanged — control group this round)
// ---------------------------------------------------------------------------
#define TBM 128
#define TBN 128
#define TBK 32
__global__ __launch_bounds__(256) void gemm3_kernel(
    const ushort_t* __restrict__ Ah, const ushort_t* __restrict__ Al,
    const ushort_t* __restrict__ Bh, const ushort_t* __restrict__ Bl,
    const float* __restrict__ bias, const float* __restrict__ res,
    float* __restrict__ C, ushort_t* __restrict__ Chi, ushort_t* __restrict__ Clo,
    int M, int N, int K)
{
    __shared__ ushort_t sAh[TBM][TBK];
    __shared__ ushort_t sAl[TBM][TBK];
    __shared__ ushort_t sBh[TBN][TBK];
    __shared__ ushort_t sBl[TBN][TBK];

    const int tid = threadIdx.x;
    const int w = tid >> 6, l = tid & 63;
    const int wr = w >> 1, wc = w & 1;
    const int m0 = blockIdx.y * TBM, n0 = blockIdx.x * TBN;
    const int lr = l & 15, lk = (l >> 4) * 8;

    f32x4 acc[4][4];
    #pragma unroll
    for (int m = 0; m < 4; ++m)
        #pragma unroll
        for (int n = 0; n < 4; ++n)
            acc[m][n] = (f32x4){0.f, 0.f, 0.f, 0.f};

    for (int k0 = 0; k0 < K; k0 += TBK) {
        if (k0) __syncthreads();
        #pragma unroll
        for (int i = 0; i < 2; ++i) {
            const int cb = i * 256 + w * 64;
            const int chunk = cb + l;
            const int row = chunk >> 2;
            const int kc = (chunk & 3) * 8;
            const size_t ga = (size_t)(m0 + row) * K + k0 + kc;
            const size_t gb = (size_t)(n0 + row) * K + k0 + kc;
            gload16(Ah + ga, &sAh[0][0] + (size_t)cb * 8);
            gload16(Al + ga, &sAl[0][0] + (size_t)cb * 8);
            gload16(Bh + gb, &sBh[0][0] + (size_t)cb * 8);
            gload16(Bl + gb, &sBl[0][0] + (size_t)cb * 8);
        }
        __syncthreads();

        bf16x8 ah[4], al[4], bh[4], bl[4];
        #pragma unroll
        for (int m = 0; m < 4; ++m) {
            ah[m] = *(const bf16x8*)&sAh[wr * 64 + m * 16 + lr][lk];
            al[m] = *(const bf16x8*)&sAl[wr * 64 + m * 16 + lr][lk];
        }
        #pragma unroll
        for (int n = 0; n < 4; ++n) {
            bh[n] = *(const bf16x8*)&sBh[wc * 64 + n * 16 + lr][lk];
            bl[n] = *(const bf16x8*)&sBl[wc * 64 + n * 16 + lr][lk];
        }
        #pragma unroll
        for (int m = 0; m < 4; ++m) {
            #pragma unroll
            for (int n = 0; n < 4; ++n) {
                acc[m][n] = MFMA16(ah[m], bh[n], acc[m][n]);
                acc[m][n] = MFMA16(al[m], bh[n], acc[m][n]);
                acc[m][n] = MFMA16(ah[m], bl[n], acc[m][n]);
            }
        }
    }

    #pragma unroll
    for (int m = 0; m < 4; ++m) {
        #pragma unroll
        for (int n = 0; n < 4; ++n) {
            const int col = n0 + wc * 64 + n * 16 + lr;
            #pragma unroll
            for (int r = 0; r < 4; ++r) {
                const int row = m0 + wr * 64 + m * 16 + (l >> 4) * 4 + r;
                const size_t o = (size_t)row * N + col;
                float v = acc[m][n][r] + bias[col];
                if (res) v += res[o];
                C[o] = v;
                if (Chi) {
                    ushort_t hv = f2bf(v);
                    Chi[o] = hv;
                    Clo[o] = f2bf(v - bf2f(hv));
                }
            }
        }
    }
}

// ---------------------------------------------------------------------------
// Fused q/k RoPE+split AND v transpose+split.  grid (S/64, H, B), 256 thr.
// q,k -> head-major [b][h][s][64] bf16 hi/lo; v -> [b][h][d][s] bf16 hi/lo.
// (u is left raw in uvqk; gate rmsnorm applies silu to it.)
// ---------------------------------------------------------------------------
__global__ __launch_bounds__(256) void qkv_kernel(
    const float* __restrict__ uvqk,
    const float* __restrict__ cosT, const float* __restrict__ sinT,
    ushort_t* __restrict__ q_hi, ushort_t* __restrict__ q_lo,
    ushort_t* __restrict__ k_hi, ushort_t* __restrict__ k_lo,
    ushort_t* __restrict__ vT_hi, ushort_t* __restrict__ vT_lo)
{
    __shared__ float T[64][65];
    const int sb = blockIdx.x, h = blockIdx.y, b = blockIdx.z;
    const int t = threadIdx.x;
    const int s0 = sb * 64;

    // ---- q/k: 4 threads per token, 8 rope-pairs each ----
    {
        const int tok = t >> 2, d0 = (t & 3) * 8;     // d0 in {0,8,16,24}
        const int bs = b * SS + s0 + tok;
        const size_t rowBase = (size_t)bs * FOURD;
        const size_t hrow = ((size_t)(b * HH + h) * SS + (s0 + tok)) * HD;
        float c[8], s[8];
        #pragma unroll
        for (int j = 0; j < 8; ++j) {
            c[j] = cosT[(size_t)bs * HD + d0 + j];
            s[j] = sinT[(size_t)bs * HD + d0 + j];
        }
        #pragma unroll
        for (int sect = 2; sect <= 3; ++sect) {
            const float* qp = uvqk + rowBase + sect * DD + h * HD;
            float a[8], bq[8];
            *(float4*)&a[0]  = *(const float4*)&qp[d0];
            *(float4*)&a[4]  = *(const float4*)&qp[d0 + 4];
            *(float4*)&bq[0] = *(const float4*)&qp[d0 + 32];
            *(float4*)&bq[4] = *(const float4*)&qp[d0 + 36];
            u32 hwL[4], lwL[4], hwH[4], lwH[4];
            #pragma unroll
            for (int j = 0; j < 4; ++j) {
                float oL0 = a[2*j] * c[2*j] - bq[2*j] * s[2*j];
                float oL1 = a[2*j+1] * c[2*j+1] - bq[2*j+1] * s[2*j+1];
                float oH0 = bq[2*j] * c[2*j] + a[2*j] * s[2*j];
                float oH1 = bq[2*j+1] * c[2*j+1] + a[2*j+1] * s[2*j+1];
                ushort_t x0 = f2bf(oL0), x1 = f2bf(oL1);
                hwL[j] = (u32)x0 | ((u32)x1 << 16);
                lwL[j] = (u32)f2bf(oL0 - bf2f(x0))
                       | ((u32)f2bf(oL1 - bf2f(x1)) << 16);
                x0 = f2bf(oH0); x1 = f2bf(oH1);
                hwH[j] = (u32)x0 | ((u32)x1 << 16);
                lwH[j] = (u32)f2bf(oH0 - bf2f(x0))
                       | ((u32)f2bf(oH1 - bf2f(x1)) << 16);
            }
            ushort_t* dh = (sect == 2) ? q_hi : k_hi;
            ushort_t* dl = (sect == 2) ? q_lo : k_lo;
            *(uint4*)&dh[hrow + d0]      = make_uint4(hwL[0], hwL[1], hwL[2], hwL[3]);
            *(uint4*)&dh[hrow + d0 + 32] = make_uint4(hwH[0], hwH[1], hwH[2], hwH[3]);
            *(uint4*)&dl[hrow + d0]      = make_uint4(lwL[0], lwL[1], lwL[2], lwL[3]);
            *(uint4*)&dl[hrow + d0 + 32] = make_uint4(lwH[0], lwH[1], lwH[2], lwH[3]);
        }
    }

    // ---- v: stage [64 s][64 d] in LDS, write transposed [d][s] ----
    #pragma unroll
    for (int it = 0; it < 4; ++it) {
        const int idx = it * 256 + t;          // 0..1023
        const int row = idx >> 4, c4 = (idx & 15) * 4;
        const float4 v = *(const float4*)&uvqk[
            (size_t)(b * SS + s0 + row) * FOURD + DD + h * HD + c4];
        T[row][c4] = v.x; T[row][c4 + 1] = v.y;
        T[row][c4 + 2] = v.z; T[row][c4 + 3] = v.w;
    }
    __syncthreads();
    {
        const int d = t >> 2, sc = (t & 3) * 16;
        u32 hw[8], lw[8];
        #pragma unroll
        for (int j = 0; j < 8; ++j) {
            const float x0 = T[sc + 2 * j][d];
            const float x1 = T[sc + 2 * j + 1][d];
            const ushort_t h0 = f2bf(x0), h1 = f2bf(x1);
            hw[j] = (u32)h0 | ((u32)h1 << 16);
            lw[j] = (u32)f2bf(x0 - bf2f(h0)) | ((u32)f2bf(x1 - bf2f(h1)) << 16);
        }
        const size_t o = ((size_t)(b * HH + h) * HD + d) * SS + s0 + sc;
        *(uint4*)&vT_hi[o] = make_uint4(hw[0], hw[1], hw[2], hw[3]);
        *(uint4*)&vT_hi[o + 8] = make_uint4(hw[4], hw[5], hw[6], hw[7]);
        *(uint4*)&vT_lo[o] = make_uint4(lw[0], lw[1], lw[2], lw[3]);
        *(uint4*)&vT_lo[o + 8] = make_uint4(lw[4], lw[5], lw[6], lw[7]);
    }
}

// ---------------------------------------------------------------------------
// MFMA causal SiLU attention. Block: 128 q-rows x (b,h); 4 waves x 32 rows.
// KVBLK = 32 keys (LDS 32KB -> 4 blocks/CU, 2x occupancy vs KVBLK=64).
// Double-buffered staging, single barrier per k-tile, setprio on MFMA.
// ---------------------------------------------------------------------------
__global__ __launch_bounds__(256) void attn_kernel(
    const ushort_t* __restrict__ q_hi, const ushort_t* __restrict__ q_lo,
    const ushort_t* __restrict__ k_hi, const ushort_t* __restrict__ k_lo,
    const ushort_t* __restrict__ vT_hi, const ushort_t* __restrict__ vT_lo,
    float* __restrict__ attnOut)
{
    __shared__ ushort_t sKh[2][32 * 64];
    __shared__ ushort_t sKl[2][32 * 64];
    __shared__ ushort_t sVh[2][64 * 32];
    __shared__ ushort_t sVl[2][64 * 32];

    const int h = blockIdx.y, b = blockIdx.z;
    const int qt = b ? blockIdx.x : (SS / 128 - 1) - blockIdx.x;  // balance
    const int tid = threadIdx.x;
    const int w = tid >> 6, l = tid & 63;
    const int lr = l & 15, g = l >> 4;

    const size_t headQ = ((size_t)(b * HH + h) * SS) * HD;
    const size_t headV = ((size_t)(b * HH + h) * HD) * SS;

    bf16x8 qh[2][2], ql[2][2];
    {
        const int qrow0 = qt * 128 + w * 32;
        #pragma unroll
        for (int qf = 0; qf < 2; ++qf)
            #pragma unroll
            for (int ds_ = 0; ds_ < 2; ++ds_) {
                const size_t off = headQ + (size_t)(qrow0 + qf * 16 + lr) * HD
                                   + ds_ * 32 + g * 8;
                qh[qf][ds_] = *(const bf16x8*)&q_hi[off];
                ql[qf][ds_] = *(const bf16x8*)&q_lo[off];
            }
    }

    f32x4 acc[2][4];
    #pragma unroll
    for (int qf = 0; qf < 2; ++qf)
        #pragma unroll
        for (int df = 0; df < 4; ++df)
            acc[qf][df] = (f32x4){0.f, 0.f, 0.f, 0.f};

    const int nkt = 4 * qt + 4;

    // per-thread staging addresses (32-key tile: K 32x64, V^T 64x32)
    const int krow = tid >> 3, kblk = tid & 7;
    const int ksb  = kblk ^ (krow & 7);
    const int vrow = tid >> 2, vblk = tid & 3;
    const int vsb  = vblk ^ (vrow & 3);

#define STAGE_TILE(pb, kt_)                                                    \
    {                                                                          \
        const ushort_t* kbh = k_hi + headQ + (size_t)(kt_) * 32 * HD;          \
        const ushort_t* kbl = k_lo + headQ + (size_t)(kt_) * 32 * HD;          \
        const ushort_t* vbh = vT_hi + headV + (kt_) * 32;                      \
        const ushort_t* vbl = vT_lo + headV + (kt_) * 32;                      \
        gload16(kbh + (size_t)krow * HD + ksb * 8, &sKh[pb][0] + (size_t)tid * 8); \
        gload16(kbl + (size_t)krow * HD + ksb * 8, &sKl[pb][0] + (size_t)tid * 8); \
        gload16(vbh + (size_t)vrow * SS + vsb * 8, &sVh[pb][0] + (size_t)tid * 8); \
        gload16(vbl + (size_t)vrow * SS + vsb * 8, &sVl[pb][0] + (size_t)tid * 8); \
    }

    STAGE_TILE(0, 0)
    __syncthreads();

    for (int kt = 0; kt < nkt; ++kt) {
        const int pb = kt & 1;
        if (kt + 1 < nkt) STAGE_TILE(pb ^ 1, kt + 1)

        // wave-level causal skip
        if (kt * 32 <= qt * 128 + w * 32 + 31) {

        // ---- QK^T (swapped): C rows = keys(32), cols = q ----
        f32x4 sc[2][2];
        #pragma unroll
        for (int f = 0; f < 2; ++f)
            #pragma unroll
            for (int qf = 0; qf < 2; ++qf)
                sc[f][qf] = (f32x4){0.f, 0.f, 0.f, 0.f};

        #pragma unroll
        for (int ds_ = 0; ds_ < 2; ++ds_) {
            bf16x8 kh[2], kl[2];
            #pragma unroll
            for (int f = 0; f < 2; ++f) {
                const int addr = (16 * f + lr) * 64 + (((4 * ds_ + g) ^ (lr & 7)) * 8);
                kh[f] = *(const bf16x8*)&sKh[pb][addr];
                kl[f] = *(const bf16x8*)&sKl[pb][addr];
            }
            __builtin_amdgcn_s_setprio(1);
            #pragma unroll
            for (int f = 0; f < 2; ++f)
                #pragma unroll
                for (int qf = 0; qf < 2; ++qf) {
                    sc[f][qf] = MFMA16(kh[f], qh[qf][ds_], sc[f][qf]);
                    sc[f][qf] = MFMA16(kl[f], qh[qf][ds_], sc[f][qf]);
                    sc[f][qf] = MFMA16(kh[f], ql[qf][ds_], sc[f][qf]);
                }
            __builtin_amdgcn_s_setprio(0);
        }

        // ---- scale + causal mask + silu + truncating pack bf16 hi/lo ----
        u32 pkh[2][2][2], pkl[2][2][2];
        #pragma unroll
        for (int f = 0; f < 2; ++f) {
            #pragma unroll
            for (int qf = 0; qf < 2; ++qf) {
                const int qrow = qt * 128 + w * 32 + qf * 16 + lr;
                float pv[4];
                #pragma unroll
                for (int r = 0; r < 4; ++r) {
                    const int key = kt * 32 + 16 * f + 4 * g + r;
                    const float x = sc[f][qf][r] * 0.125f;
                    pv[r] = (key <= qrow) ? silu_fast(x) : 0.0f;
                }
                #pragma unroll
                for (int t2 = 0; t2 < 2; ++t2) {
                    const u32 u0 = __float_as_uint(pv[2 * t2]);
                    const u32 u1 = __float_as_uint(pv[2 * t2 + 1]);
                    const u32 h0 = u0 >> 16, h1 = u1 >> 16;
                    pkh[f][qf][t2] = h0 | (h1 << 16);
                    const float l0 = pv[2 * t2]     - __uint_as_float(h0 << 16);
                    const float l1 = pv[2 * t2 + 1] - __uint_as_float(h1 << 16);
                    pkl[f][qf][t2] = (__float_as_uint(l0) >> 16)
                                   | ((__float_as_uint(l1) >> 16) << 16);
                }
            }
        }

        // ---- PV (single 32-key slab) ----
        {
            U8 ah[2], al[2];
            #pragma unroll
            for (int qf = 0; qf < 2; ++qf) {
                #pragma unroll
                for (int d = 0; d < 4; ++d) {
                    const int srcLane = lr + 16 * (2 * (g & 1) + (d >> 1));
                    const int t2 = d & 1;
                    int x0 = __shfl((int)pkh[0][qf][t2], srcLane, 64);
                    int x1 = __shfl((int)pkh[1][qf][t2], srcLane, 64);
                    ah[qf].d[d] = (g & 2) ? x1 : x0;
                    x0 = __shfl((int)pkl[0][qf][t2], srcLane, 64);
                    x1 = __shfl((int)pkl[1][qf][t2], srcLane, 64);
                    al[qf].d[d] = (g & 2) ? x1 : x0;
                }
            }
            #pragma unroll
            for (int df = 0; df < 4; ++df) {
                const int vaddr = (16 * df + lr) * 32 + ((g ^ (lr & 3)) * 8);
                const bf16x8 vh = *(const bf16x8*)&sVh[pb][vaddr];
                const bf16x8 vl = *(const bf16x8*)&sVl[pb][vaddr];
                __builtin_amdgcn_s_setprio(1);
                #pragma unroll
                for (int qf = 0; qf < 2; ++qf) {
                    acc[qf][df] = MFMA16(ah[qf].v, vh, acc[qf][df]);
                    acc[qf][df] = MFMA16(al[qf].v, vh, acc[qf][df]);
                    acc[qf][df] = MFMA16(ah[qf].v, vl, acc[qf][df]);
                }
                __builtin_amdgcn_s_setprio(0);
            }
        }

        } // end causal-skip

        __syncthreads();   // stage(kt+1) drained + all waves done with buf pb
    }

    #pragma unroll
    for (int qf = 0; qf < 2; ++qf) {
        #pragma unroll
        for (int df = 0; df < 4; ++df) {
            #pragma unroll
            for (int r = 0; r < 4; ++r) {
                const int row = qt * 128 + w * 32 + qf * 16 + 4 * g + r;
                attnOut[(size_t)(b * SS + row) * DD + h * HD + 16 * df + lr]
                    = acc[qf][df][r];
            }
        }
    }
#undef STAGE_TILE
}

// ---------------------------------------------------------------------------
// launch
// ---------------------------------------------------------------------------
extern "C" void kernel_launch(void* const* d_in, const int* in_sizes, int n_in,
                              void* d_out, int out_size, void* d_ws, size_t ws_size,
                              hipStream_t stream) {
    const float* x           = (const float*)d_in[0];
    const float* td          = (const float*)d_in[1];
    const float* uvqk_w      = (const float*)d_in[3];
    const float* uvqk_b      = (const float*)d_in[4];
    const float* gate_w      = (const float*)d_in[5];
    const float* out_w       = (const float*)d_in[6];
    const float* out_b       = (const float*)d_in[7];
    const float* in_norm_w   = (const float*)d_in[8];
    const float* last_norm_w = (const float*)d_in[9];
    const int*   pid         = (const int*)d_in[10];
    float* out = (float*)d_out;
    char*  ws  = (char*)d_ws;

    const size_t QKV = (size_t)BB * HH * SS * HD;      // 4.19M elems

    float* cosT = (float*)ws;                          ws += (size_t)BS * HD * 4;
    float* sinT = (float*)ws;                          ws += (size_t)BS * HD * 4;
    float* h    = (float*)ws;                          ws += (size_t)BS * DD * 4;
    float* uvqk = (float*)ws;                          ws += (size_t)BS * FOURD * 4;
    float* attn = (float*)ws;                          ws += (size_t)BS * DD * 4;
    ushort_t* h_hi  = (ushort_t*)ws;                   ws += (size_t)BS * DD * 2;
    ushort_t* h_lo  = (ushort_t*)ws;                   ws += (size_t)BS * DD * 2;
    ushort_t* g_hi  = (ushort_t*)ws;                   ws += (size_t)BS * DD * 2;
    ushort_t* g_lo  = (ushort_t*)ws;                   ws += (size_t)BS * DD * 2;
    ushort_t* uWt_hi = (ushort_t*)ws;                  ws += (size_t)FOURD * DD * 2;
    ushort_t* uWt_lo = (ushort_t*)ws;                  ws += (size_t)FOURD * DD * 2;
    ushort_t* oWt_hi = (ushort_t*)ws;                  ws += (size_t)DD * DD * 2;
    ushort_t* oWt_lo = (ushort_t*)ws;                  ws += (size_t)DD * DD * 2;
    ushort_t* q_hi  = (ushort_t*)ws;                   ws += QKV * 2;
    ushort_t* q_lo  = (ushort_t*)ws;                   ws += QKV * 2;
    ushort_t* k_hi  = (ushort_t*)ws;                   ws += QKV * 2;
    ushort_t* k_lo  = (ushort_t*)ws;                   ws += QKV * 2;
    ushort_t* vT_hi = (ushort_t*)ws;                   ws += QKV * 2;
    ushort_t* vT_lo = (ushort_t*)ws;                   ws += QKV * 2;
    (void)ws_size;

    rope_table_kernel<<<(BS * 32 + 255) / 256, 256, 0, stream>>>(td, pid, cosT, sinT);
    rmsnorm_kernel<<<BS, 256, 0, stream>>>(x, in_norm_w, nullptr, 0, 0, h, h_hi, h_lo);

    for (int l = 0; l < LL; ++l) {
        wsplit_kernel<<<dim3(FOURD / 32, DD / 32), 256, 0, stream>>>(
            uvqk_w + (size_t)l * DD * FOURD, uWt_hi, uWt_lo, DD, FOURD);
        gemm3_kernel<<<dim3(FOURD / TBN, BS / TBM), 256, 0, stream>>>(
            h_hi, h_lo, uWt_hi, uWt_lo, uvqk_b + (size_t)l * FOURD,
            nullptr, uvqk, nullptr, nullptr, BS, FOURD, DD);
        qkv_kernel<<<dim3(SS / 64, HH, BB), 256, 0, stream>>>(
            uvqk, cosT, sinT, q_hi, q_lo, k_hi, k_lo, vT_hi, vT_lo);
        attn_kernel<<<dim3(SS / 128, HH, BB), 256, 0, stream>>>(
            q_hi, q_lo, k_hi, k_lo, vT_hi, vT_lo, attn);
        // gated = rmsnorm(attn, gate_w) * silu(u)   (u raw in uvqk)
        rmsnorm_kernel<<<BS, 256, 0, stream>>>(
            attn, gate_w + (size_t)l * DD, uvqk, FOURD, 1, attn, g_hi, g_lo);
        wsplit_kernel<<<dim3(DD / 32, DD / 32), 256, 0, stream>>>(
            out_w + (size_t)l * DD * DD, oWt_hi, oWt_lo, DD, DD);
        gemm3_kernel<<<dim3(DD / TBN, BS / TBM), 256, 0, stream>>>(
            g_hi, g_lo, oWt_hi, oWt_lo, out_b + (size_t)l * DD,
            h, h, h_hi, h_lo, BS, DD, DD);
    }

    rmsnorm_kernel<<<BS, 256, 0, stream>>>(h, last_norm_w, nullptr, 0, 0, out, nullptr, nullptr);
}